// Round 2
// baseline (3394.791 us; speedup 1.0000x reference)
//
#include <hip/hip_runtime.h>
#include <hip/hip_bf16.h>

#define N_ 100000
#define E_ 300000
#define ETOT 400000
#define G_ 2048
#define HID_ 256
#define NB_SCAN 98        // ceil(N_/1024)
#define CHUNK_E 25000     // 12 exact chunks of E_
#define N_CHUNKS 12

// ---------------- mean of edge_attr over rows -> meansum[64] (sum; divide later)
__global__ __launch_bounds__(256) void mean_kernel(const float* __restrict__ ea, float* __restrict__ meansum) {
    __shared__ float s[256];
    int tid = threadIdx.x;
    int col = tid & 63, rg = tid >> 6;
    float acc = 0.f;
    for (long long row = (long long)blockIdx.x * 4 + rg; row < E_; row += (long long)gridDim.x * 4)
        acc += ea[row * 64 + col];
    s[tid] = acc;
    __syncthreads();
    if (tid < 64) atomicAdd(meansum + tid, s[tid] + s[tid + 64] + s[tid + 128] + s[tid + 192]);
}

// ---------------- loop_e[c] = (meansum/E) @ We_l   (the self-loop edge row, per layer)
__global__ __launch_bounds__(256) void loope_kernel(const float* __restrict__ meansum,
                                                    const float* __restrict__ We_l,
                                                    float* __restrict__ loope) {
    int c = threadIdx.x;
    float acc = 0.f;
    const float invE = 1.0f / (float)E_;
    for (int k = 0; k < 64; k++) acc += (meansum[k] * invE) * We_l[k * 256 + c];
    loope[c] = acc;
}

// ---------------- CSR build over dst (self loops e>=E_ have dst = e-E_)
__global__ __launch_bounds__(256) void hist_kernel(const int* __restrict__ ei, int* __restrict__ deg) {
    int e = blockIdx.x * 256 + threadIdx.x;
    if (e >= ETOT) return;
    int d = (e < E_) ? ei[E_ + e] : (e - E_);
    atomicAdd(deg + d, 1);
}

__global__ __launch_bounds__(256) void scanA_kernel(const int* __restrict__ deg, int* __restrict__ off,
                                                    int* __restrict__ bsum) {
    __shared__ int s[256];
    int tid = threadIdx.x;
    int base = blockIdx.x * 1024 + tid * 4;
    int v[4];
#pragma unroll
    for (int i = 0; i < 4; i++) v[i] = (base + i < N_) ? deg[base + i] : 0;
    v[1] += v[0]; v[2] += v[1]; v[3] += v[2];
    s[tid] = v[3];
    __syncthreads();
    for (int o = 1; o < 256; o <<= 1) {
        int t = (tid >= o) ? s[tid - o] : 0;
        __syncthreads();
        s[tid] += t;
        __syncthreads();
    }
    int prev = tid ? s[tid - 1] : 0;
#pragma unroll
    for (int i = 0; i < 4; i++)
        if (base + i < N_) off[base + i + 1] = prev + v[i];
    if (tid == 255) bsum[blockIdx.x] = s[255];
}

__global__ void scanB_kernel(int* __restrict__ bsum) {
    if (threadIdx.x == 0) {
        int run = 0;
        for (int i = 0; i < NB_SCAN; i++) { int t = bsum[i]; bsum[i] = run; run += t; }
    }
}

__global__ __launch_bounds__(256) void scanC_kernel(int* __restrict__ off, const int* __restrict__ bsum) {
    int i = blockIdx.x * 256 + threadIdx.x;
    if (i < N_) {
        off[i + 1] += bsum[i >> 10];
        if (i == 0) off[0] = 0;
    }
}

__global__ __launch_bounds__(256) void scatter_kernel(const int* __restrict__ ei, int* __restrict__ cursor,
                                                      int* __restrict__ csr) {
    int e = blockIdx.x * 256 + threadIdx.x;
    if (e >= ETOT) return;
    int d = (e < E_) ? ei[E_ + e] : (e - E_);
    int pos = atomicAdd(cursor + d, 1);
    csr[pos] = e;
}

// ---------------- tiled SGEMM: C[M,256] = A[M,K] @ B[K,256] (+bias), fp32
// In-place safe for C==A: each block reads only rows [m0,m0+64) and writes
// the same rows, all reads complete before the epilogue stores.
#define BM 64
#define BK 32
__global__ __launch_bounds__(256) void gemm_kernel(const float* __restrict__ A, const float* __restrict__ B,
                                                   const float* __restrict__ bias, float* __restrict__ C,
                                                   int M, int K) {
    __shared__ float As[BM][36];     // row stride 144 B = 9*16 B -> float4-aligned
    __shared__ float Bs[BK][256];
    const int tid = threadIdx.x;
    const int tx = tid & 63;   // column group: cols tx*4 .. tx*4+3
    const int ty = tid >> 6;   // row group: rows ty*16 .. ty*16+15
    const int m0 = blockIdx.x * BM;
    float acc[16][4];
#pragma unroll
    for (int r = 0; r < 16; r++)
#pragma unroll
        for (int j = 0; j < 4; j++) acc[r][j] = 0.f;

    for (int k0 = 0; k0 < K; k0 += BK) {
#pragma unroll
        for (int i = 0; i < 2; i++) {
            int li = tid + i * 256;          // 0..511 -> 64 rows x 8 col-groups
            int row = li >> 3;
            int cg = li & 7;
            int gr = m0 + row;
            float4 v = make_float4(0.f, 0.f, 0.f, 0.f);
            if (gr < M) v = *(const float4*)(A + (size_t)gr * K + k0 + cg * 4);
            *(float4*)(&As[row][cg * 4]) = v;
        }
#pragma unroll
        for (int i = 0; i < 8; i++) {
            int li = tid + i * 256;          // 0..2047 -> 32 rows x 64 col-groups
            int row = li >> 6;
            int c4 = li & 63;
            float4 v = *(const float4*)(B + (size_t)(k0 + row) * 256 + c4 * 4);
            *(float4*)(&Bs[row][c4 * 4]) = v;
        }
        __syncthreads();
#pragma unroll
        for (int kk = 0; kk < BK; kk += 4) {
            float4 b0 = *(const float4*)(&Bs[kk + 0][tx * 4]);
            float4 b1 = *(const float4*)(&Bs[kk + 1][tx * 4]);
            float4 b2 = *(const float4*)(&Bs[kk + 2][tx * 4]);
            float4 b3 = *(const float4*)(&Bs[kk + 3][tx * 4]);
#pragma unroll
            for (int r = 0; r < 16; r++) {
                float4 a = *(const float4*)(&As[ty * 16 + r][kk]);
                acc[r][0] += a.x * b0.x; acc[r][1] += a.x * b0.y; acc[r][2] += a.x * b0.z; acc[r][3] += a.x * b0.w;
                acc[r][0] += a.y * b1.x; acc[r][1] += a.y * b1.y; acc[r][2] += a.y * b1.z; acc[r][3] += a.y * b1.w;
                acc[r][0] += a.z * b2.x; acc[r][1] += a.z * b2.y; acc[r][2] += a.z * b2.z; acc[r][3] += a.z * b2.w;
                acc[r][0] += a.w * b3.x; acc[r][1] += a.w * b3.y; acc[r][2] += a.w * b3.z; acc[r][3] += a.w * b3.w;
            }
        }
        __syncthreads();
    }
    float4 bv = make_float4(0.f, 0.f, 0.f, 0.f);
    if (bias) bv = *(const float4*)(bias + tx * 4);
#pragma unroll
    for (int r = 0; r < 16; r++) {
        int gr = m0 + ty * 16 + r;
        if (gr < M) {
            float4 o;
            o.x = acc[r][0] + bv.x; o.y = acc[r][1] + bv.y; o.z = acc[r][2] + bv.z; o.w = acc[r][3] + bv.w;
            *(float4*)(C + (size_t)gr * 256 + tx * 4) = o;
        }
    }
}

// ---------------- float <-> order-preserving uint key for atomicMax
__device__ __forceinline__ unsigned fkey(float f) {
    unsigned u = __float_as_uint(f);
    return (u & 0x80000000u) ? ~u : (u | 0x80000000u);
}
__device__ __forceinline__ float funkey(unsigned key) {
    return (key & 0x80000000u) ? __uint_as_float(key & 0x7fffffffu) : __uint_as_float(~key);
}

// ---------------- per-edge logits + segment max, for a chunk of real edges
__global__ __launch_bounds__(256) void logits_chunk_kernel(const float* __restrict__ xl, const float* __restrict__ xr,
                                                           const float* __restrict__ ematc, const float* __restrict__ att,
                                                           const int* __restrict__ ei, int c0,
                                                           float* __restrict__ logits, unsigned* __restrict__ lmaxkey) {
    int wid = threadIdx.x >> 6;
    int lane = threadIdx.x & 63;
    int el = blockIdx.x * 4 + wid;
    if (el >= CHUNK_E) return;
    int e = c0 + el;
    int s = ei[e];
    int d = ei[E_ + e];
    const float* erow = ematc + (size_t)el * 256;
    const float* xls = xl + (size_t)s * 256;
    const float* xrd = xr + (size_t)d * 256;
    float r[4];
#pragma unroll
    for (int j = 0; j < 4; j++) {
        int t = j * 64 + lane;
        float m = xls[t] + xrd[t] + erow[t];
        m = (m > 0.f) ? m : 0.2f * m;
        r[j] = m * att[t];
    }
#pragma unroll
    for (int o = 32; o; o >>= 1) {
#pragma unroll
        for (int j = 0; j < 4; j++) r[j] += __shfl_xor(r[j], o, 64);
    }
    if (lane == 0) {
#pragma unroll
        for (int j = 0; j < 4; j++) {
            logits[(size_t)e * 4 + j] = r[j];
            atomicMax(lmaxkey + (size_t)d * 4 + j, fkey(r[j]));
        }
    }
}

// ---------------- self-loop logits (edge id E_+n, src=dst=n, erow=loope)
__global__ __launch_bounds__(256) void self_logits_kernel(const float* __restrict__ xl, const float* __restrict__ xr,
                                                          const float* __restrict__ loope, const float* __restrict__ att,
                                                          float* __restrict__ logits, unsigned* __restrict__ lmaxkey) {
    int wid = threadIdx.x >> 6;
    int lane = threadIdx.x & 63;
    int n = blockIdx.x * 4 + wid;
    if (n >= N_) return;
    const float* xls = xl + (size_t)n * 256;
    const float* xrd = xr + (size_t)n * 256;
    float r[4];
#pragma unroll
    for (int j = 0; j < 4; j++) {
        int t = j * 64 + lane;
        float m = xls[t] + xrd[t] + loope[t];
        m = (m > 0.f) ? m : 0.2f * m;
        r[j] = m * att[t];
    }
#pragma unroll
    for (int o = 32; o; o >>= 1) {
#pragma unroll
        for (int j = 0; j < 4; j++) r[j] += __shfl_xor(r[j], o, 64);
    }
    if (lane == 0) {
#pragma unroll
        for (int j = 0; j < 4; j++) {
            logits[(size_t)(E_ + n) * 4 + j] = r[j];
            atomicMax(lmaxkey + (size_t)n * 4 + j, fkey(r[j]));
        }
    }
}

// ---------------- p = exp(logit - lmax[dst]); denom[dst] += p
__global__ __launch_bounds__(256) void pden_kernel(const int* __restrict__ ei, float* __restrict__ plog,
                                                   const unsigned* __restrict__ lmaxkey, float* __restrict__ denom) {
    int idx = blockIdx.x * 256 + threadIdx.x;
    if (idx >= ETOT * 4) return;
    int e = idx >> 2, j = idx & 3;
    int d = (e < E_) ? ei[E_ + e] : (e - E_);
    float lm = funkey(lmaxkey[(size_t)d * 4 + j]);
    float p = expf(plog[idx] - lm);
    plog[idx] = p;
    atomicAdd(denom + (size_t)d * 4 + j, p);
}

// ---------------- CSR aggregation: xout[d] = relu( sum_e alpha*xl[src] + bias )
// Reads xl/plog/denom only; xout may alias the xr buffer.
__global__ __launch_bounds__(256) void agg_kernel(const float* __restrict__ xl, const float* __restrict__ plog,
                                                  const float* __restrict__ denom, const int* __restrict__ off,
                                                  const int* __restrict__ csr, const int* __restrict__ ei,
                                                  const float* __restrict__ bias, float* __restrict__ xout) {
    int d = blockIdx.x;
    int t = threadIdx.x;
    int h = t >> 6;
    float den = denom[(size_t)d * 4 + h] + 1e-16f;
    int s0 = off[d], s1 = off[d + 1];
    float acc = 0.f;
    for (int i = s0; i < s1; i++) {
        int e = csr[i];
        int s = (e < E_) ? ei[e] : (e - E_);
        float alpha = plog[(size_t)e * 4 + h] / den;
        acc += alpha * xl[(size_t)s * 256 + t];
    }
    float v = acc + bias[t];
    xout[(size_t)d * 256 + t] = v > 0.f ? v : 0.f;
}

// ---------------- per-graph mean pool + 2-layer MLP head
__device__ __forceinline__ int lbound(const int* __restrict__ a, int n, int v) {
    int lo = 0, hi = n;
    while (lo < hi) { int mid = (lo + hi) >> 1; if (a[mid] < v) lo = mid + 1; else hi = mid; }
    return lo;
}

__global__ __launch_bounds__(256) void pool_mlp_kernel(const float* __restrict__ x, const int* __restrict__ batch,
                                                       const float* __restrict__ Wp1, const float* __restrict__ bp1,
                                                       const float* __restrict__ Wp2, const float* __restrict__ bp2,
                                                       float* __restrict__ out) {
    int g = blockIdx.x;
    int t = threadIdx.x;
    int lo = lbound(batch, N_, g);
    int hi = lbound(batch, N_, g + 1);
    float sum = 0.f;
    for (int n = lo; n < hi; n++) sum += x[(size_t)n * 256 + t];
    int cnt = hi - lo;
    float pooled = sum / (float)(cnt > 1 ? cnt : 1);
    __shared__ float sp[256];
    __shared__ float sh[128];
    __shared__ float sw[4];
    sp[t] = pooled;
    __syncthreads();
    if (t < 128) {
        float a = bp1[t];
        for (int k = 0; k < 256; k++) a += sp[k] * Wp1[k * 128 + t];
        sh[t] = a > 0.f ? a : 0.f;
    }
    __syncthreads();
    float v = (t < 128) ? sh[t] * Wp2[t] : 0.f;
#pragma unroll
    for (int o = 32; o; o >>= 1) v += __shfl_xor(v, o, 64);
    if ((t & 63) == 0) sw[t >> 6] = v;
    __syncthreads();
    if (t == 0) out[g] = sw[0] + sw[1] + sw[2] + sw[3] + bp2[0];
}

// ---------------- workspace layout (bytes), total ~241 MB
#define B0_OFF   ((size_t)0)                               // xl            102.4 MB
#define B1_OFF   (B0_OFF + (size_t)N_ * 256 * 4)           // xr / xout     102.4 MB
#define EM_OFF   (B1_OFF + (size_t)N_ * 256 * 4)           // emat chunk     25.6 MB
#define LG_OFF   (EM_OFF + (size_t)CHUNK_E * 256 * 4)      // logits/p        6.4 MB
#define LM_OFF   (LG_OFF + (size_t)ETOT * 4 * 4)           // lmax keys       1.6 MB
#define DN_OFF   (LM_OFF + (size_t)N_ * 4 * 4)             // denom           1.6 MB
#define DG_OFF   (DN_OFF + (size_t)N_ * 4 * 4)             // deg             0.4 MB
#define OF_OFF   (DG_OFF + (size_t)N_ * 4)                 // off             0.4 MB
#define CU_OFF   (OF_OFF + (size_t)(N_ + 32) * 4)          // cursor          0.4 MB
#define CS_OFF   (CU_OFF + (size_t)N_ * 4)                 // csr             1.6 MB
#define BS_OFF   (CS_OFF + (size_t)ETOT * 4)
#define MS_OFF   (BS_OFF + (size_t)512)
#define LE_OFF   (MS_OFF + (size_t)256)

extern "C" void kernel_launch(void* const* d_in, const int* in_sizes, int n_in,
                              void* d_out, int out_size, void* d_ws, size_t ws_size,
                              hipStream_t stream) {
    const float* x     = (const float*)d_in[0];
    const int*   ei    = (const int*)d_in[1];    // [2,E]: first E = src, next E = dst
    const float* eattr = (const float*)d_in[2];
    const int*   batch = (const int*)d_in[3];
    const float* Wl    = (const float*)d_in[4];
    const float* bl    = (const float*)d_in[5];
    const float* Wr    = (const float*)d_in[6];
    const float* br    = (const float*)d_in[7];
    const float* We    = (const float*)d_in[8];
    const float* att   = (const float*)d_in[9];
    const float* bias  = (const float*)d_in[10];
    const float* Wp1   = (const float*)d_in[11];
    const float* bp1   = (const float*)d_in[12];
    const float* Wp2   = (const float*)d_in[13];
    const float* bp2   = (const float*)d_in[14];

    char* ws = (char*)d_ws;
    float*    xl      = (float*)(ws + B0_OFF);
    float*    buf1    = (float*)(ws + B1_OFF);    // xr, then overwritten as layer output
    float*    ematc   = (float*)(ws + EM_OFF);
    float*    plog    = (float*)(ws + LG_OFF);
    unsigned* lmaxkey = (unsigned*)(ws + LM_OFF);
    float*    denom   = (float*)(ws + DN_OFF);
    int*      deg     = (int*)(ws + DG_OFF);
    int*      off     = (int*)(ws + OF_OFF);
    int*      cursor  = (int*)(ws + CU_OFF);
    int*      csr     = (int*)(ws + CS_OFF);
    int*      bsum    = (int*)(ws + BS_OFF);
    float*    meansum = (float*)(ws + MS_OFF);
    float*    loope   = (float*)(ws + LE_OFF);

    // setup: mean(edge_attr) and CSR by dst (dst is layer-invariant)
    hipMemsetAsync(meansum, 0, 64 * 4, stream);
    hipMemsetAsync(deg, 0, (size_t)N_ * 4, stream);
    mean_kernel<<<512, 256, 0, stream>>>(eattr, meansum);
    hist_kernel<<<(ETOT + 255) / 256, 256, 0, stream>>>(ei, deg);
    scanA_kernel<<<NB_SCAN, 256, 0, stream>>>(deg, off, bsum);
    scanB_kernel<<<1, 64, 0, stream>>>(bsum);
    scanC_kernel<<<(N_ + 255) / 256, 256, 0, stream>>>(off, bsum);
    hipMemcpyAsync(cursor, off, (size_t)N_ * 4, hipMemcpyDeviceToDevice, stream);
    scatter_kernel<<<(ETOT + 255) / 256, 256, 0, stream>>>(ei, cursor, csr);

    const int gemm_blocks_N = (N_ + BM - 1) / BM;       // 1563
    const int gemm_blocks_C = (CHUNK_E + BM - 1) / BM;  // 391

    for (int l = 0; l < 3; l++) {
        const float* xin = (l == 0) ? x : buf1;
        const float* We_l = We + (size_t)l * 64 * 256;
        const float* att_l = att + (size_t)l * 256;
        loope_kernel<<<1, 256, 0, stream>>>(meansum, We_l, loope);
        // xl <- xin @ Wl + bl   (distinct buffers)
        gemm_kernel<<<gemm_blocks_N, 256, 0, stream>>>(xin, Wl + (size_t)l * 256 * 256, bl + (size_t)l * 256, xl, N_, 256);
        // xr <- xin @ Wr + br   (in-place over buf1 for l>0; block-row-local, safe)
        gemm_kernel<<<gemm_blocks_N, 256, 0, stream>>>(xin, Wr + (size_t)l * 256 * 256, br + (size_t)l * 256, buf1, N_, 256);
        hipMemsetAsync(lmaxkey, 0, (size_t)N_ * 4 * 4, stream);
        hipMemsetAsync(denom, 0, (size_t)N_ * 4 * 4, stream);
        // chunked edge transform + logits (emat chunk stays in LLC)
        for (int c = 0; c < N_CHUNKS; c++) {
            int c0 = c * CHUNK_E;
            gemm_kernel<<<gemm_blocks_C, 256, 0, stream>>>(eattr + (size_t)c0 * 64, We_l, nullptr, ematc, CHUNK_E, 64);
            logits_chunk_kernel<<<(CHUNK_E + 3) / 4, 256, 0, stream>>>(xl, buf1, ematc, att_l, ei, c0, plog, lmaxkey);
        }
        self_logits_kernel<<<(N_ + 3) / 4, 256, 0, stream>>>(xl, buf1, loope, att_l, plog, lmaxkey);
        pden_kernel<<<(ETOT * 4 + 255) / 256, 256, 0, stream>>>(ei, plog, lmaxkey, denom);
        // xout -> buf1 (overwrites xr; agg does not read xr)
        agg_kernel<<<N_, 256, 0, stream>>>(xl, plog, denom, off, csr, ei, bias + (size_t)l * 256, buf1);
    }

    pool_mlp_kernel<<<G_, 256, 0, stream>>>(buf1, batch, Wp1, bp1, Wp2, bp2, (float*)d_out);
}

// Round 3
// 2735.998 us; speedup vs baseline: 1.2408x; 1.2408x over previous
//
#include <hip/hip_runtime.h>
#include <hip/hip_bf16.h>

#define N_ 100000
#define E_ 300000
#define ETOT 400000
#define G_ 2048
#define NB_SCAN 98        // ceil(N_/1024)
#define CHUNK_E 25000     // 12 exact chunks of E_
#define N_CHUNKS 12

typedef __attribute__((ext_vector_type(8))) short bf16x8;
typedef __attribute__((ext_vector_type(4))) float f32x4;

__device__ __forceinline__ short f2bf(float f) {
    __hip_bfloat16 h = __float2bfloat16(f);
    return *reinterpret_cast<short*>(&h);
}
__device__ __forceinline__ float bf2f(short s) {
    __hip_bfloat16 h = *reinterpret_cast<__hip_bfloat16*>(&s);
    return __bfloat162float(h);
}

// ---------------- mean of edge_attr over rows -> meansum[64] (sum; divide later)
__global__ __launch_bounds__(256) void mean_kernel(const float* __restrict__ ea, float* __restrict__ meansum) {
    __shared__ float s[256];
    int tid = threadIdx.x;
    int col = tid & 63, rg = tid >> 6;
    float acc = 0.f;
    for (long long row = (long long)blockIdx.x * 4 + rg; row < E_; row += (long long)gridDim.x * 4)
        acc += ea[row * 64 + col];
    s[tid] = acc;
    __syncthreads();
    if (tid < 64) atomicAdd(meansum + tid, s[tid] + s[tid + 64] + s[tid + 128] + s[tid + 192]);
}

// ---------------- loop_e[c] = (meansum/E) @ We_l   (self-loop edge row, per layer)
__global__ __launch_bounds__(256) void loope_kernel(const float* __restrict__ meansum,
                                                    const float* __restrict__ We_l,
                                                    float* __restrict__ loope) {
    int c = threadIdx.x;
    float acc = 0.f;
    const float invE = 1.0f / (float)E_;
    for (int k = 0; k < 64; k++) acc += (meansum[k] * invE) * We_l[k * 256 + c];
    loope[c] = acc;
}

// ---------------- weight prep: split fp32 -> (hi,lo) bf16, transposed to [n][k]
// Wcat^T: [l][512 n][256 k]; n<256 from Wl, n>=256 from Wr
__global__ __launch_bounds__(256) void prep_wcat_kernel(const float* __restrict__ Wl, const float* __restrict__ Wr,
                                                        short* __restrict__ hi, short* __restrict__ lo) {
    int idx = blockIdx.x * 256 + threadIdx.x;
    if (idx >= 3 * 512 * 256) return;
    int l = idx / (512 * 256);
    int rem = idx % (512 * 256);
    int n = rem >> 8, k = rem & 255;
    float v = (n < 256) ? Wl[((size_t)l * 256 + k) * 256 + n]
                        : Wr[((size_t)l * 256 + k) * 256 + (n - 256)];
    short h = f2bf(v);
    hi[idx] = h;
    lo[idx] = f2bf(v - bf2f(h));
}

// We^T: [l][256 n][64 k]
__global__ __launch_bounds__(256) void prep_we_kernel(const float* __restrict__ We,
                                                      short* __restrict__ hi, short* __restrict__ lo) {
    int idx = blockIdx.x * 256 + threadIdx.x;
    if (idx >= 3 * 256 * 64) return;
    int l = idx / (256 * 64);
    int rem = idx % (256 * 64);
    int n = rem >> 6, k = rem & 63;
    float v = We[((size_t)l * 64 + k) * 256 + n];
    short h = f2bf(v);
    hi[idx] = h;
    lo[idx] = f2bf(v - bf2f(h));
}

// ---------------- CSR build over dst (self loops e>=E_ have dst = e-E_)
__global__ __launch_bounds__(256) void hist_kernel(const int* __restrict__ ei, int* __restrict__ deg) {
    int e = blockIdx.x * 256 + threadIdx.x;
    if (e >= ETOT) return;
    int d = (e < E_) ? ei[E_ + e] : (e - E_);
    atomicAdd(deg + d, 1);
}

__global__ __launch_bounds__(256) void scanA_kernel(const int* __restrict__ deg, int* __restrict__ off,
                                                    int* __restrict__ bsum) {
    __shared__ int s[256];
    int tid = threadIdx.x;
    int base = blockIdx.x * 1024 + tid * 4;
    int v[4];
#pragma unroll
    for (int i = 0; i < 4; i++) v[i] = (base + i < N_) ? deg[base + i] : 0;
    v[1] += v[0]; v[2] += v[1]; v[3] += v[2];
    s[tid] = v[3];
    __syncthreads();
    for (int o = 1; o < 256; o <<= 1) {
        int t = (tid >= o) ? s[tid - o] : 0;
        __syncthreads();
        s[tid] += t;
        __syncthreads();
    }
    int prev = tid ? s[tid - 1] : 0;
#pragma unroll
    for (int i = 0; i < 4; i++)
        if (base + i < N_) off[base + i + 1] = prev + v[i];
    if (tid == 255) bsum[blockIdx.x] = s[255];
}

__global__ void scanB_kernel(int* __restrict__ bsum) {
    if (threadIdx.x == 0) {
        int run = 0;
        for (int i = 0; i < NB_SCAN; i++) { int t = bsum[i]; bsum[i] = run; run += t; }
    }
}

__global__ __launch_bounds__(256) void scanC_kernel(int* __restrict__ off, const int* __restrict__ bsum) {
    int i = blockIdx.x * 256 + threadIdx.x;
    if (i < N_) {
        off[i + 1] += bsum[i >> 10];
        if (i == 0) off[0] = 0;
    }
}

__global__ __launch_bounds__(256) void scatter_kernel(const int* __restrict__ ei, int* __restrict__ cursor,
                                                      int* __restrict__ csr) {
    int e = blockIdx.x * 256 + threadIdx.x;
    if (e >= ETOT) return;
    int d = (e < E_) ? ei[E_ + e] : (e - E_);
    int pos = atomicAdd(cursor + d, 1);
    csr[pos] = e;
}

// ---------------- split-bf16 MFMA GEMM
// C[M,*] = A[M,K](fp32) @ B[K,N] via B^T(hi/lo bf16, [n][k]) with 3-product split:
// A_hi*B_hi + A_hi*B_lo + A_lo*B_hi  (A split in-kernel during LDS staging).
// Block tile 128m x 128n, 4 waves (2x2 of 64x64), 16x16x32 MFMA.
// Output: global col n0 = blockIdx.y*128; if n0>=256 -> C1 (col-256), else C0. ldc=256.
#define BM 128
#define BK 32
#define LDK 40   // padded k-stride in shorts (80 B: 16B-aligned, ~2-way banks)

__global__ __launch_bounds__(256, 2) void mfma_gemm_kernel(
    const float* __restrict__ A,
    const short* __restrict__ Bt_hi, const short* __restrict__ Bt_lo,
    float* __restrict__ C0, float* __restrict__ C1,
    const float* __restrict__ bias0, const float* __restrict__ bias1,
    int M, int K) {
    __shared__ short Ahi[BM * LDK];
    __shared__ short Alo[BM * LDK];
    __shared__ short Bhi[BM * LDK];
    __shared__ short Blo[BM * LDK];

    const int tid = threadIdx.x;
    const int m0 = blockIdx.x * BM;
    const int n0 = blockIdx.y * BM;
    const int wave = tid >> 6, lane = tid & 63;
    const int wm = (wave >> 1) * 64, wn = (wave & 1) * 64;
    const int r = lane & 15, q = lane >> 4;

    f32x4 acc[4][4];
#pragma unroll
    for (int i = 0; i < 4; i++)
#pragma unroll
        for (int j = 0; j < 4; j++) acc[i][j] = (f32x4){0.f, 0.f, 0.f, 0.f};

    for (int k0 = 0; k0 < K; k0 += BK) {
        // ---- stage A (fp32 -> hi/lo bf16): 128 rows x 32 k
#pragma unroll
        for (int i = 0; i < 4; i++) {
            int li = i * 256 + tid;          // 0..1023
            int row = li >> 3, kg = li & 7;  // 4 floats each
            int gm = m0 + row;
            float4 v = make_float4(0.f, 0.f, 0.f, 0.f);
            if (gm < M) v = *(const float4*)(A + (size_t)gm * K + k0 + kg * 4);
            float f[4] = {v.x, v.y, v.z, v.w};
            short h[4], l[4];
#pragma unroll
            for (int j = 0; j < 4; j++) {
                h[j] = f2bf(f[j]);
                l[j] = f2bf(f[j] - bf2f(h[j]));
            }
            *(short4*)(&Ahi[row * LDK + kg * 4]) = make_short4(h[0], h[1], h[2], h[3]);
            *(short4*)(&Alo[row * LDK + kg * 4]) = make_short4(l[0], l[1], l[2], l[3]);
        }
        // ---- stage B^T hi/lo: 128 n-rows x 32 k (bf16, 16B chunks)
#pragma unroll
        for (int i = 0; i < 2; i++) {
            int li = i * 256 + tid;          // 0..511
            int row = li >> 2, kg = li & 3;  // 8 shorts each
            size_t gofs = (size_t)(n0 + row) * K + k0 + kg * 8;
            *(bf16x8*)(&Bhi[row * LDK + kg * 8]) = *(const bf16x8*)(Bt_hi + gofs);
            *(bf16x8*)(&Blo[row * LDK + kg * 8]) = *(const bf16x8*)(Bt_lo + gofs);
        }
        __syncthreads();
        // ---- 3 split products over the same staged tiles
#pragma unroll
        for (int pass = 0; pass < 3; pass++) {
            const short* Abuf = (pass == 2) ? Alo : Ahi;
            const short* Bbuf = (pass == 1) ? Blo : Bhi;
            bf16x8 af[4], bfr[4];
#pragma unroll
            for (int f = 0; f < 4; f++) {
                af[f]  = *(const bf16x8*)(Abuf + (wm + f * 16 + r) * LDK + q * 8);
                bfr[f] = *(const bf16x8*)(Bbuf + (wn + f * 16 + r) * LDK + q * 8);
            }
#pragma unroll
            for (int fm = 0; fm < 4; fm++)
#pragma unroll
                for (int fn = 0; fn < 4; fn++)
                    acc[fm][fn] = __builtin_amdgcn_mfma_f32_16x16x32_bf16(af[fm], bfr[fn], acc[fm][fn], 0, 0, 0);
        }
        __syncthreads();
    }

    // ---- epilogue: C/D map col=lane&15, row=q*4+reg
    float* C = C0;
    const float* bs = bias0;
    int ncol = n0;
    if (n0 >= 256) { C = C1; bs = bias1; ncol = n0 - 256; }
#pragma unroll
    for (int fm = 0; fm < 4; fm++) {
#pragma unroll
        for (int fn = 0; fn < 4; fn++) {
            int col = ncol + wn + fn * 16 + r;
            float bv = bs ? bs[col] : 0.f;
#pragma unroll
            for (int g = 0; g < 4; g++) {
                int row = m0 + wm + fm * 16 + q * 4 + g;
                if (row < M) C[(size_t)row * 256 + col] = acc[fm][fn][g] + bv;
            }
        }
    }
}

// ---------------- float <-> order-preserving uint key for atomicMax
__device__ __forceinline__ unsigned fkey(float f) {
    unsigned u = __float_as_uint(f);
    return (u & 0x80000000u) ? ~u : (u | 0x80000000u);
}
__device__ __forceinline__ float funkey(unsigned key) {
    return (key & 0x80000000u) ? __uint_as_float(key & 0x7fffffffu) : __uint_as_float(~key);
}

// ---------------- per-edge logits + segment max, for a chunk of real edges
__global__ __launch_bounds__(256) void logits_chunk_kernel(const float* __restrict__ xl, const float* __restrict__ xr,
                                                           const float* __restrict__ ematc, const float* __restrict__ att,
                                                           const int* __restrict__ ei, int c0,
                                                           float* __restrict__ logits, unsigned* __restrict__ lmaxkey) {
    int wid = threadIdx.x >> 6;
    int lane = threadIdx.x & 63;
    int el = blockIdx.x * 4 + wid;
    if (el >= CHUNK_E) return;
    int e = c0 + el;
    int s = ei[e];
    int d = ei[E_ + e];
    const float* erow = ematc + (size_t)el * 256;
    const float* xls = xl + (size_t)s * 256;
    const float* xrd = xr + (size_t)d * 256;
    float r[4];
#pragma unroll
    for (int j = 0; j < 4; j++) {
        int t = j * 64 + lane;
        float m = xls[t] + xrd[t] + erow[t];
        m = (m > 0.f) ? m : 0.2f * m;
        r[j] = m * att[t];
    }
#pragma unroll
    for (int o = 32; o; o >>= 1) {
#pragma unroll
        for (int j = 0; j < 4; j++) r[j] += __shfl_xor(r[j], o, 64);
    }
    if (lane == 0) {
#pragma unroll
        for (int j = 0; j < 4; j++) {
            logits[(size_t)e * 4 + j] = r[j];
            atomicMax(lmaxkey + (size_t)d * 4 + j, fkey(r[j]));
        }
    }
}

// ---------------- self-loop logits (edge id E_+n, src=dst=n, erow=loope)
__global__ __launch_bounds__(256) void self_logits_kernel(const float* __restrict__ xl, const float* __restrict__ xr,
                                                          const float* __restrict__ loope, const float* __restrict__ att,
                                                          float* __restrict__ logits, unsigned* __restrict__ lmaxkey) {
    int wid = threadIdx.x >> 6;
    int lane = threadIdx.x & 63;
    int n = blockIdx.x * 4 + wid;
    if (n >= N_) return;
    const float* xls = xl + (size_t)n * 256;
    const float* xrd = xr + (size_t)n * 256;
    float r[4];
#pragma unroll
    for (int j = 0; j < 4; j++) {
        int t = j * 64 + lane;
        float m = xls[t] + xrd[t] + loope[t];
        m = (m > 0.f) ? m : 0.2f * m;
        r[j] = m * att[t];
    }
#pragma unroll
    for (int o = 32; o; o >>= 1) {
#pragma unroll
        for (int j = 0; j < 4; j++) r[j] += __shfl_xor(r[j], o, 64);
    }
    if (lane == 0) {
#pragma unroll
        for (int j = 0; j < 4; j++) {
            logits[(size_t)(E_ + n) * 4 + j] = r[j];
            atomicMax(lmaxkey + (size_t)n * 4 + j, fkey(r[j]));
        }
    }
}

// ---------------- p = exp(logit - lmax[dst]); denom[dst] += p
__global__ __launch_bounds__(256) void pden_kernel(const int* __restrict__ ei, float* __restrict__ plog,
                                                   const unsigned* __restrict__ lmaxkey, float* __restrict__ denom) {
    int idx = blockIdx.x * 256 + threadIdx.x;
    if (idx >= ETOT * 4) return;
    int e = idx >> 2, j = idx & 3;
    int d = (e < E_) ? ei[E_ + e] : (e - E_);
    float lm = funkey(lmaxkey[(size_t)d * 4 + j]);
    float p = expf(plog[idx] - lm);
    plog[idx] = p;
    atomicAdd(denom + (size_t)d * 4 + j, p);
}

// ---------------- CSR aggregation: xout[d] = relu( sum_e alpha*xl[src] + bias )
__global__ __launch_bounds__(256) void agg_kernel(const float* __restrict__ xl, const float* __restrict__ plog,
                                                  const float* __restrict__ denom, const int* __restrict__ off,
                                                  const int* __restrict__ csr, const int* __restrict__ ei,
                                                  const float* __restrict__ bias, float* __restrict__ xout) {
    int d = blockIdx.x;
    int t = threadIdx.x;
    int h = t >> 6;
    float den = denom[(size_t)d * 4 + h] + 1e-16f;
    int s0 = off[d], s1 = off[d + 1];
    float acc = 0.f;
    for (int i = s0; i < s1; i++) {
        int e = csr[i];
        int s = (e < E_) ? ei[e] : (e - E_);
        float alpha = plog[(size_t)e * 4 + h] / den;
        acc += alpha * xl[(size_t)s * 256 + t];
    }
    float v = acc + bias[t];
    xout[(size_t)d * 256 + t] = v > 0.f ? v : 0.f;
}

// ---------------- per-graph mean pool + 2-layer MLP head
__device__ __forceinline__ int lbound(const int* __restrict__ a, int n, int v) {
    int lo = 0, hi = n;
    while (lo < hi) { int mid = (lo + hi) >> 1; if (a[mid] < v) lo = mid + 1; else hi = mid; }
    return lo;
}

__global__ __launch_bounds__(256) void pool_mlp_kernel(const float* __restrict__ x, const int* __restrict__ batch,
                                                       const float* __restrict__ Wp1, const float* __restrict__ bp1,
                                                       const float* __restrict__ Wp2, const float* __restrict__ bp2,
                                                       float* __restrict__ out) {
    int g = blockIdx.x;
    int t = threadIdx.x;
    int lo = lbound(batch, N_, g);
    int hi = lbound(batch, N_, g + 1);
    float sum = 0.f;
    for (int n = lo; n < hi; n++) sum += x[(size_t)n * 256 + t];
    int cnt = hi - lo;
    float pooled = sum / (float)(cnt > 1 ? cnt : 1);
    __shared__ float sp[256];
    __shared__ float sh[128];
    __shared__ float sw[4];
    sp[t] = pooled;
    __syncthreads();
    if (t < 128) {
        float a = bp1[t];
        for (int k = 0; k < 256; k++) a += sp[k] * Wp1[k * 128 + t];
        sh[t] = a > 0.f ? a : 0.f;
    }
    __syncthreads();
    float v = (t < 128) ? sh[t] * Wp2[t] : 0.f;
#pragma unroll
    for (int o = 32; o; o >>= 1) v += __shfl_xor(v, o, 64);
    if ((t & 63) == 0) sw[t >> 6] = v;
    __syncthreads();
    if (t == 0) out[g] = sw[0] + sw[1] + sw[2] + sw[3] + bp2[0];
}

// ---------------- workspace layout (bytes), total ~345 MB
#define W0_OFF   ((size_t)0)                               // A / agg out   102.4 MB
#define W1_OFF   (W0_OFF + (size_t)N_ * 256 * 4)           // xl            102.4 MB
#define W2_OFF   (W1_OFF + (size_t)N_ * 256 * 4)           // xr            102.4 MB
#define EM_OFF   (W2_OFF + (size_t)N_ * 256 * 4)           // emat chunk     25.6 MB
#define LG_OFF   (EM_OFF + (size_t)CHUNK_E * 256 * 4)      // logits/p        6.4 MB
#define LM_OFF   (LG_OFF + (size_t)ETOT * 4 * 4)           // lmax keys       1.6 MB
#define DN_OFF   (LM_OFF + (size_t)N_ * 4 * 4)             // denom           1.6 MB
#define DG_OFF   (DN_OFF + (size_t)N_ * 4 * 4)             // deg
#define OF_OFF   (DG_OFF + (size_t)N_ * 4)                 // off
#define CU_OFF   (OF_OFF + (size_t)(N_ + 32) * 4)          // cursor
#define CS_OFF   (CU_OFF + (size_t)N_ * 4)                 // csr
#define BS_OFF   (CS_OFF + (size_t)ETOT * 4)
#define MS_OFF   (BS_OFF + (size_t)512)
#define LE_OFF   (MS_OFF + (size_t)256)
#define WCH_OFF  (LE_OFF + (size_t)2048)                   // Wcat^T hi: 3*512*256 shorts
#define WCL_OFF  (WCH_OFF + (size_t)3 * 512 * 256 * 2)
#define WEH_OFF  (WCL_OFF + (size_t)3 * 512 * 256 * 2)     // We^T hi: 3*256*64 shorts
#define WEL_OFF  (WEH_OFF + (size_t)3 * 256 * 64 * 2)

extern "C" void kernel_launch(void* const* d_in, const int* in_sizes, int n_in,
                              void* d_out, int out_size, void* d_ws, size_t ws_size,
                              hipStream_t stream) {
    const float* x     = (const float*)d_in[0];
    const int*   ei    = (const int*)d_in[1];    // [2,E]: first E = src, next E = dst
    const float* eattr = (const float*)d_in[2];
    const int*   batch = (const int*)d_in[3];
    const float* Wl    = (const float*)d_in[4];
    const float* bl    = (const float*)d_in[5];
    const float* Wr    = (const float*)d_in[6];
    const float* br    = (const float*)d_in[7];
    const float* We    = (const float*)d_in[8];
    const float* att   = (const float*)d_in[9];
    const float* bias  = (const float*)d_in[10];
    const float* Wp1   = (const float*)d_in[11];
    const float* bp1   = (const float*)d_in[12];
    const float* Wp2   = (const float*)d_in[13];
    const float* bp2   = (const float*)d_in[14];

    char* ws = (char*)d_ws;
    float*    w0      = (float*)(ws + W0_OFF);   // GEMM A input (layers 1,2) / agg output
    float*    xl      = (float*)(ws + W1_OFF);
    float*    xr      = (float*)(ws + W2_OFF);
    float*    ematc   = (float*)(ws + EM_OFF);
    float*    plog    = (float*)(ws + LG_OFF);
    unsigned* lmaxkey = (unsigned*)(ws + LM_OFF);
    float*    denom   = (float*)(ws + DN_OFF);
    int*      deg     = (int*)(ws + DG_OFF);
    int*      off     = (int*)(ws + OF_OFF);
    int*      cursor  = (int*)(ws + CU_OFF);
    int*      csr     = (int*)(ws + CS_OFF);
    int*      bsum    = (int*)(ws + BS_OFF);
    float*    meansum = (float*)(ws + MS_OFF);
    float*    loope   = (float*)(ws + LE_OFF);
    short*    wcatH   = (short*)(ws + WCH_OFF);
    short*    wcatL   = (short*)(ws + WCL_OFF);
    short*    weH     = (short*)(ws + WEH_OFF);
    short*    weL     = (short*)(ws + WEL_OFF);

    // setup: mean(edge_attr), weight split/transpose, CSR by dst
    hipMemsetAsync(meansum, 0, 64 * 4, stream);
    hipMemsetAsync(deg, 0, (size_t)N_ * 4, stream);
    mean_kernel<<<512, 256, 0, stream>>>(eattr, meansum);
    prep_wcat_kernel<<<(3 * 512 * 256 + 255) / 256, 256, 0, stream>>>(Wl, Wr, wcatH, wcatL);
    prep_we_kernel<<<(3 * 256 * 64 + 255) / 256, 256, 0, stream>>>(We, weH, weL);
    hist_kernel<<<(ETOT + 255) / 256, 256, 0, stream>>>(ei, deg);
    scanA_kernel<<<NB_SCAN, 256, 0, stream>>>(deg, off, bsum);
    scanB_kernel<<<1, 64, 0, stream>>>(bsum);
    scanC_kernel<<<(N_ + 255) / 256, 256, 0, stream>>>(off, bsum);
    hipMemcpyAsync(cursor, off, (size_t)N_ * 4, hipMemcpyDeviceToDevice, stream);
    scatter_kernel<<<(ETOT + 255) / 256, 256, 0, stream>>>(ei, cursor, csr);

    const dim3 gemmN_grid((N_ + BM - 1) / BM, 4);       // 782 x 4 (xl|xr fused, N=512)
    const dim3 gemmE_grid((CHUNK_E + BM - 1) / BM, 2);  // 196 x 2 (N=256)

    for (int l = 0; l < 3; l++) {
        const float* xin = (l == 0) ? x : w0;
        const float* We_l = We + (size_t)l * 64 * 256;
        const float* att_l = att + (size_t)l * 256;
        loope_kernel<<<1, 256, 0, stream>>>(meansum, We_l, loope);
        // fused xl|xr: C0=xl (cols 0..255 of concat), C1=xr
        mfma_gemm_kernel<<<gemmN_grid, 256, 0, stream>>>(
            xin, wcatH + (size_t)l * 512 * 256, wcatL + (size_t)l * 512 * 256,
            xl, xr, bl + (size_t)l * 256, br + (size_t)l * 256, N_, 256);
        hipMemsetAsync(lmaxkey, 0, (size_t)N_ * 4 * 4, stream);
        hipMemsetAsync(denom, 0, (size_t)N_ * 4 * 4, stream);
        for (int c = 0; c < N_CHUNKS; c++) {
            int c0 = c * CHUNK_E;
            mfma_gemm_kernel<<<gemmE_grid, 256, 0, stream>>>(
                eattr + (size_t)c0 * 64, weH + (size_t)l * 256 * 64, weL + (size_t)l * 256 * 64,
                ematc, nullptr, nullptr, nullptr, CHUNK_E, 64);
            logits_chunk_kernel<<<(CHUNK_E + 3) / 4, 256, 0, stream>>>(xl, xr, ematc, att_l, ei, c0, plog, lmaxkey);
        }
        self_logits_kernel<<<(N_ + 3) / 4, 256, 0, stream>>>(xl, xr, loope, att_l, plog, lmaxkey);
        pden_kernel<<<(ETOT * 4 + 255) / 256, 256, 0, stream>>>(ei, plog, lmaxkey, denom);
        agg_kernel<<<N_, 256, 0, stream>>>(xl, plog, denom, off, csr, ei, bias + (size_t)l * 256, w0);
    }

    pool_mlp_kernel<<<G_, 256, 0, stream>>>(w0, batch, Wp1, bp1, Wp2, bp2, (float*)d_out);
}

// Round 4
// 2427.480 us; speedup vs baseline: 1.3985x; 1.1271x over previous
//
#include <hip/hip_runtime.h>
#include <hip/hip_bf16.h>

#define N_ 100000
#define E_ 300000
#define ETOT 400000
#define G_ 2048
#define NB_SCAN 98        // ceil(N_/1024)
#define CHUNK_E 50000     // 6 exact chunks of E_
#define N_CHUNKS 6

typedef __attribute__((ext_vector_type(8))) short bf16x8;
typedef __attribute__((ext_vector_type(4))) float f32x4;

__device__ __forceinline__ short f2bf(float f) {
    __hip_bfloat16 h = __float2bfloat16(f);
    return *reinterpret_cast<short*>(&h);
}
__device__ __forceinline__ float bf2f(short s) {
    __hip_bfloat16 h = *reinterpret_cast<__hip_bfloat16*>(&s);
    return __bfloat162float(h);
}

// ---------------- mean of edge_attr over rows -> meansum[64] (sum; divide later)
__global__ __launch_bounds__(256) void mean_kernel(const float* __restrict__ ea, float* __restrict__ meansum) {
    __shared__ float s[256];
    int tid = threadIdx.x;
    int col = tid & 63, rg = tid >> 6;
    float acc = 0.f;
    for (long long row = (long long)blockIdx.x * 4 + rg; row < E_; row += (long long)gridDim.x * 4)
        acc += ea[row * 64 + col];
    s[tid] = acc;
    __syncthreads();
    if (tid < 64) atomicAdd(meansum + tid, s[tid] + s[tid + 64] + s[tid + 128] + s[tid + 192]);
}

// ---------------- loop_e[c] = (meansum/E) @ We_l   (self-loop edge row, per layer)
__global__ __launch_bounds__(256) void loope_kernel(const float* __restrict__ meansum,
                                                    const float* __restrict__ We_l,
                                                    float* __restrict__ loope) {
    int c = threadIdx.x;
    float acc = 0.f;
    const float invE = 1.0f / (float)E_;
    for (int k = 0; k < 64; k++) acc += (meansum[k] * invE) * We_l[k * 256 + c];
    loope[c] = acc;
}

// ---------------- weight prep: split fp32 -> (hi,lo) bf16, transposed to [n][k]
__global__ __launch_bounds__(256) void prep_wcat_kernel(const float* __restrict__ Wl, const float* __restrict__ Wr,
                                                        short* __restrict__ hi, short* __restrict__ lo) {
    int idx = blockIdx.x * 256 + threadIdx.x;
    if (idx >= 3 * 512 * 256) return;
    int l = idx / (512 * 256);
    int rem = idx % (512 * 256);
    int n = rem >> 8, k = rem & 255;
    float v = (n < 256) ? Wl[((size_t)l * 256 + k) * 256 + n]
                        : Wr[((size_t)l * 256 + k) * 256 + (n - 256)];
    short h = f2bf(v);
    hi[idx] = h;
    lo[idx] = f2bf(v - bf2f(h));
}

__global__ __launch_bounds__(256) void prep_we_kernel(const float* __restrict__ We,
                                                      short* __restrict__ hi, short* __restrict__ lo) {
    int idx = blockIdx.x * 256 + threadIdx.x;
    if (idx >= 3 * 256 * 64) return;
    int l = idx / (256 * 64);
    int rem = idx % (256 * 64);
    int n = rem >> 6, k = rem & 63;
    float v = We[((size_t)l * 64 + k) * 256 + n];
    short h = f2bf(v);
    hi[idx] = h;
    lo[idx] = f2bf(v - bf2f(h));
}

// ---------------- CSR build over dst (self loops e>=E_ have dst = e-E_)
__global__ __launch_bounds__(256) void hist_kernel(const int* __restrict__ ei, int* __restrict__ deg) {
    int e = blockIdx.x * 256 + threadIdx.x;
    if (e >= ETOT) return;
    int d = (e < E_) ? ei[E_ + e] : (e - E_);
    atomicAdd(deg + d, 1);
}

__global__ __launch_bounds__(256) void scanA_kernel(const int* __restrict__ deg, int* __restrict__ off,
                                                    int* __restrict__ bsum) {
    __shared__ int s[256];
    int tid = threadIdx.x;
    int base = blockIdx.x * 1024 + tid * 4;
    int v[4];
#pragma unroll
    for (int i = 0; i < 4; i++) v[i] = (base + i < N_) ? deg[base + i] : 0;
    v[1] += v[0]; v[2] += v[1]; v[3] += v[2];
    s[tid] = v[3];
    __syncthreads();
    for (int o = 1; o < 256; o <<= 1) {
        int t = (tid >= o) ? s[tid - o] : 0;
        __syncthreads();
        s[tid] += t;
        __syncthreads();
    }
    int prev = tid ? s[tid - 1] : 0;
#pragma unroll
    for (int i = 0; i < 4; i++)
        if (base + i < N_) off[base + i + 1] = prev + v[i];
    if (tid == 255) bsum[blockIdx.x] = s[255];
}

__global__ void scanB_kernel(int* __restrict__ bsum) {
    if (threadIdx.x == 0) {
        int run = 0;
        for (int i = 0; i < NB_SCAN; i++) { int t = bsum[i]; bsum[i] = run; run += t; }
    }
}

__global__ __launch_bounds__(256) void scanC_kernel(int* __restrict__ off, const int* __restrict__ bsum) {
    int i = blockIdx.x * 256 + threadIdx.x;
    if (i < N_) {
        off[i + 1] += bsum[i >> 10];
        if (i == 0) off[0] = 0;
    }
}

// scatter: csr[pos]=edge id; srcs[pos]=src node; pose[e]=pos
__global__ __launch_bounds__(256) void scatter_kernel(const int* __restrict__ ei, int* __restrict__ cursor,
                                                      int* __restrict__ csr, int* __restrict__ srcs,
                                                      int* __restrict__ pose) {
    int e = blockIdx.x * 256 + threadIdx.x;
    if (e >= ETOT) return;
    int s, d;
    if (e < E_) { s = ei[e]; d = ei[E_ + e]; }
    else        { s = e - E_; d = s; }
    int pos = atomicAdd(cursor + d, 1);
    csr[pos] = e;
    srcs[pos] = s;
    pose[e] = pos;
}

// ---------------- split-bf16 MFMA GEMM
// C[M,*] = A[M,K](fp32) @ B^T(hi/lo bf16 [n][k]); 3 products Ahi*Bhi+Ahi*Blo+Alo*Bhi.
// Tile 128x128, 4 waves (2x2 of 64x64), 16x16x32 MFMA.
// n0<256 -> C0(fp32, opt) + C0b(bf16, opt), bias0; n0>=256 -> C1b(bf16), bias1. ldc=256.
#define BM 128
#define BK 32
#define LDK 40

__global__ __launch_bounds__(256, 2) void mfma_gemm_kernel(
    const float* __restrict__ A,
    const short* __restrict__ Bt_hi, const short* __restrict__ Bt_lo,
    float* __restrict__ C0, short* __restrict__ C0b, short* __restrict__ C1b,
    const float* __restrict__ bias0, const float* __restrict__ bias1,
    int M, int K) {
    __shared__ short Ahi[BM * LDK];
    __shared__ short Alo[BM * LDK];
    __shared__ short Bhi[BM * LDK];
    __shared__ short Blo[BM * LDK];

    const int tid = threadIdx.x;
    const int m0 = blockIdx.x * BM;
    const int n0 = blockIdx.y * BM;
    const int wave = tid >> 6, lane = tid & 63;
    const int wm = (wave >> 1) * 64, wn = (wave & 1) * 64;
    const int r = lane & 15, q = lane >> 4;

    f32x4 acc[4][4];
#pragma unroll
    for (int i = 0; i < 4; i++)
#pragma unroll
        for (int j = 0; j < 4; j++) acc[i][j] = (f32x4){0.f, 0.f, 0.f, 0.f};

    for (int k0 = 0; k0 < K; k0 += BK) {
#pragma unroll
        for (int i = 0; i < 4; i++) {
            int li = i * 256 + tid;
            int row = li >> 3, kg = li & 7;
            int gm = m0 + row;
            float4 v = make_float4(0.f, 0.f, 0.f, 0.f);
            if (gm < M) v = *(const float4*)(A + (size_t)gm * K + k0 + kg * 4);
            float f[4] = {v.x, v.y, v.z, v.w};
            short h[4], l[4];
#pragma unroll
            for (int j = 0; j < 4; j++) {
                h[j] = f2bf(f[j]);
                l[j] = f2bf(f[j] - bf2f(h[j]));
            }
            *(short4*)(&Ahi[row * LDK + kg * 4]) = make_short4(h[0], h[1], h[2], h[3]);
            *(short4*)(&Alo[row * LDK + kg * 4]) = make_short4(l[0], l[1], l[2], l[3]);
        }
#pragma unroll
        for (int i = 0; i < 2; i++) {
            int li = i * 256 + tid;
            int row = li >> 2, kg = li & 3;
            size_t gofs = (size_t)(n0 + row) * K + k0 + kg * 8;
            *(bf16x8*)(&Bhi[row * LDK + kg * 8]) = *(const bf16x8*)(Bt_hi + gofs);
            *(bf16x8*)(&Blo[row * LDK + kg * 8]) = *(const bf16x8*)(Bt_lo + gofs);
        }
        __syncthreads();
#pragma unroll
        for (int pass = 0; pass < 3; pass++) {
            const short* Abuf = (pass == 2) ? Alo : Ahi;
            const short* Bbuf = (pass == 1) ? Blo : Bhi;
            bf16x8 af[4], bfr[4];
#pragma unroll
            for (int f = 0; f < 4; f++) {
                af[f]  = *(const bf16x8*)(Abuf + (wm + f * 16 + r) * LDK + q * 8);
                bfr[f] = *(const bf16x8*)(Bbuf + (wn + f * 16 + r) * LDK + q * 8);
            }
#pragma unroll
            for (int fm = 0; fm < 4; fm++)
#pragma unroll
                for (int fn = 0; fn < 4; fn++)
                    acc[fm][fn] = __builtin_amdgcn_mfma_f32_16x16x32_bf16(af[fm], bfr[fn], acc[fm][fn], 0, 0, 0);
        }
        __syncthreads();
    }

    // epilogue: C/D map col=lane&15, row=q*4+reg
    const bool second = (n0 >= 256);
    const int ncol = second ? n0 - 256 : n0;
    const float* bs = second ? bias1 : bias0;
#pragma unroll
    for (int fm = 0; fm < 4; fm++) {
#pragma unroll
        for (int fn = 0; fn < 4; fn++) {
            int col = ncol + wn + fn * 16 + r;
            float bv = bs ? bs[col] : 0.f;
#pragma unroll
            for (int g = 0; g < 4; g++) {
                int row = m0 + wm + fm * 16 + q * 4 + g;
                if (row < M) {
                    float v = acc[fm][fn][g] + bv;
                    size_t o = (size_t)row * 256 + col;
                    if (second) {
                        C1b[o] = f2bf(v);
                    } else {
                        if (C0)  C0[o] = v;
                        if (C0b) C0b[o] = f2bf(v);
                    }
                }
            }
        }
    }
}

// ---------------- float <-> order-preserving uint key for atomicMax
__device__ __forceinline__ unsigned fkey(float f) {
    unsigned u = __float_as_uint(f);
    return (u & 0x80000000u) ? ~u : (u | 0x80000000u);
}
__device__ __forceinline__ float funkey(unsigned key) {
    return (key & 0x80000000u) ? __uint_as_float(key & 0x7fffffffu) : __uint_as_float(~key);
}

// ---------------- per-edge logits + segment max (bf16 inputs, fp32 math)
__global__ __launch_bounds__(256) void logits_chunk_kernel(const short* __restrict__ xlb, const short* __restrict__ xrb,
                                                           const short* __restrict__ ematb, const float* __restrict__ att,
                                                           const int* __restrict__ ei, int c0,
                                                           float* __restrict__ logits, unsigned* __restrict__ lmaxkey) {
    int wid = threadIdx.x >> 6;
    int lane = threadIdx.x & 63;
    int el = blockIdx.x * 4 + wid;
    if (el >= CHUNK_E) return;
    int e = c0 + el;
    int s = ei[e];
    int d = ei[E_ + e];
    const short* erow = ematb + (size_t)el * 256;
    const short* xls = xlb + (size_t)s * 256;
    const short* xrd = xrb + (size_t)d * 256;
    float r[4];
#pragma unroll
    for (int j = 0; j < 4; j++) {
        int t = j * 64 + lane;
        float m = bf2f(xls[t]) + bf2f(xrd[t]) + bf2f(erow[t]);
        m = (m > 0.f) ? m : 0.2f * m;
        r[j] = m * att[t];
    }
#pragma unroll
    for (int o = 32; o; o >>= 1) {
#pragma unroll
        for (int j = 0; j < 4; j++) r[j] += __shfl_xor(r[j], o, 64);
    }
    if (lane == 0) {
#pragma unroll
        for (int j = 0; j < 4; j++) {
            logits[(size_t)e * 4 + j] = r[j];
            atomicMax(lmaxkey + (size_t)d * 4 + j, fkey(r[j]));
        }
    }
}

// ---------------- self-loop logits (edge id E_+n, src=dst=n, erow=loope fp32)
__global__ __launch_bounds__(256) void self_logits_kernel(const short* __restrict__ xlb, const short* __restrict__ xrb,
                                                          const float* __restrict__ loope, const float* __restrict__ att,
                                                          float* __restrict__ logits, unsigned* __restrict__ lmaxkey) {
    int wid = threadIdx.x >> 6;
    int lane = threadIdx.x & 63;
    int n = blockIdx.x * 4 + wid;
    if (n >= N_) return;
    const short* xls = xlb + (size_t)n * 256;
    const short* xrd = xrb + (size_t)n * 256;
    float r[4];
#pragma unroll
    for (int j = 0; j < 4; j++) {
        int t = j * 64 + lane;
        float m = bf2f(xls[t]) + bf2f(xrd[t]) + loope[t];
        m = (m > 0.f) ? m : 0.2f * m;
        r[j] = m * att[t];
    }
#pragma unroll
    for (int o = 32; o; o >>= 1) {
#pragma unroll
        for (int j = 0; j < 4; j++) r[j] += __shfl_xor(r[j], o, 64);
    }
    if (lane == 0) {
#pragma unroll
        for (int j = 0; j < 4; j++) {
            logits[(size_t)(E_ + n) * 4 + j] = r[j];
            atomicMax(lmaxkey + (size_t)n * 4 + j, fkey(r[j]));
        }
    }
}

// ---------------- p = exp(logit - lmax[dst]); denom[dst] += p
__global__ __launch_bounds__(256) void pden_kernel(const int* __restrict__ ei, float* __restrict__ plog,
                                                   const unsigned* __restrict__ lmaxkey, float* __restrict__ denom) {
    int idx = blockIdx.x * 256 + threadIdx.x;
    if (idx >= ETOT * 4) return;
    int e = idx >> 2, j = idx & 3;
    int d = (e < E_) ? ei[E_ + e] : (e - E_);
    float lm = funkey(lmaxkey[(size_t)d * 4 + j]);
    float p = expf(plog[idx] - lm);
    plog[idx] = p;
    atomicAdd(denom + (size_t)d * 4 + j, p);
}

// ---------------- alpha_csr[pos][h] = p / denom[dst]  (CSR-slot indexed)
__global__ __launch_bounds__(256) void alpha_kernel(const int* __restrict__ ei, const int* __restrict__ pose,
                                                    const float* __restrict__ plog, const float* __restrict__ denom,
                                                    float* __restrict__ alpha) {
    int idx = blockIdx.x * 256 + threadIdx.x;
    if (idx >= ETOT * 4) return;
    int e = idx >> 2, j = idx & 3;
    int d = (e < E_) ? ei[E_ + e] : (e - E_);
    int pos = pose[e];
    alpha[(size_t)pos * 4 + j] = plog[idx] / (denom[(size_t)d * 4 + j] + 1e-16f);
}

// ---------------- CSR aggregation: xout[d] = relu( sum_i alpha[i]*xl[srcs[i]] + bias )
__global__ __launch_bounds__(256) void agg_kernel(const float* __restrict__ xl, const float* __restrict__ alpha,
                                                  const int* __restrict__ off, const int* __restrict__ srcs,
                                                  const float* __restrict__ bias, float* __restrict__ xout) {
    int d = blockIdx.x;
    int t = threadIdx.x;
    int h = t >> 6;
    int s0 = off[d], s1 = off[d + 1];
    float acc = 0.f;
    int i = s0;
    for (; i + 4 <= s1; i += 4) {
        int a0 = srcs[i], a1 = srcs[i + 1], a2 = srcs[i + 2], a3 = srcs[i + 3];
        float w0 = alpha[(size_t)i * 4 + h];
        float w1 = alpha[(size_t)(i + 1) * 4 + h];
        float w2 = alpha[(size_t)(i + 2) * 4 + h];
        float w3 = alpha[(size_t)(i + 3) * 4 + h];
        float x0 = xl[(size_t)a0 * 256 + t];
        float x1 = xl[(size_t)a1 * 256 + t];
        float x2 = xl[(size_t)a2 * 256 + t];
        float x3 = xl[(size_t)a3 * 256 + t];
        acc += w0 * x0 + w1 * x1 + w2 * x2 + w3 * x3;
    }
    for (; i < s1; i++)
        acc += alpha[(size_t)i * 4 + h] * xl[(size_t)srcs[i] * 256 + t];
    float v = acc + bias[t];
    xout[(size_t)d * 256 + t] = v > 0.f ? v : 0.f;
}

// ---------------- per-graph mean pool + 2-layer MLP head
__device__ __forceinline__ int lbound(const int* __restrict__ a, int n, int v) {
    int lo = 0, hi = n;
    while (lo < hi) { int mid = (lo + hi) >> 1; if (a[mid] < v) lo = mid + 1; else hi = mid; }
    return lo;
}

__global__ __launch_bounds__(256) void pool_mlp_kernel(const float* __restrict__ x, const int* __restrict__ batch,
                                                       const float* __restrict__ Wp1, const float* __restrict__ bp1,
                                                       const float* __restrict__ Wp2, const float* __restrict__ bp2,
                                                       float* __restrict__ out) {
    int g = blockIdx.x;
    int t = threadIdx.x;
    int lo = lbound(batch, N_, g);
    int hi = lbound(batch, N_, g + 1);
    float sum = 0.f;
    for (int n = lo; n < hi; n++) sum += x[(size_t)n * 256 + t];
    int cnt = hi - lo;
    float pooled = sum / (float)(cnt > 1 ? cnt : 1);
    __shared__ float sp[256];
    __shared__ float sh[128];
    __shared__ float sw[4];
    sp[t] = pooled;
    __syncthreads();
    if (t < 128) {
        float a = bp1[t];
        for (int k = 0; k < 256; k++) a += sp[k] * Wp1[k * 128 + t];
        sh[t] = a > 0.f ? a : 0.f;
    }
    __syncthreads();
    float v = (t < 128) ? sh[t] * Wp2[t] : 0.f;
#pragma unroll
    for (int o = 32; o; o >>= 1) v += __shfl_xor(v, o, 64);
    if ((t & 63) == 0) sw[t >> 6] = v;
    __syncthreads();
    if (t == 0) out[g] = sw[0] + sw[1] + sw[2] + sw[3] + bp2[0];
}

// ---------------- workspace layout (bytes), total ~356 MB
#define W0_OFF   ((size_t)0)                               // layer io      102.4 MB
#define XL_OFF   (W0_OFF + (size_t)N_ * 256 * 4)           // xl fp32       102.4 MB
#define XLB_OFF  (XL_OFF + (size_t)N_ * 256 * 4)           // xl bf16        51.2 MB
#define XRB_OFF  (XLB_OFF + (size_t)N_ * 256 * 2)          // xr bf16        51.2 MB
#define EMB_OFF  (XRB_OFF + (size_t)N_ * 256 * 2)          // emat chunk bf16 25.6 MB
#define LG_OFF   (EMB_OFF + (size_t)CHUNK_E * 256 * 2)     // plog            6.4 MB
#define AL_OFF   (LG_OFF + (size_t)ETOT * 4 * 4)           // alpha_csr       6.4 MB
#define LM_OFF   (AL_OFF + (size_t)ETOT * 4 * 4)           // lmax keys
#define DN_OFF   (LM_OFF + (size_t)N_ * 4 * 4)             // denom
#define DG_OFF   (DN_OFF + (size_t)N_ * 4 * 4)             // deg
#define OF_OFF   (DG_OFF + (size_t)N_ * 4)                 // off
#define CU_OFF   (OF_OFF + (size_t)(N_ + 32) * 4)          // cursor
#define CS_OFF   (CU_OFF + (size_t)N_ * 4)                 // csr
#define SR_OFF   (CS_OFF + (size_t)ETOT * 4)               // srcs
#define PE_OFF   (SR_OFF + (size_t)ETOT * 4)               // pose
#define BS_OFF   (PE_OFF + (size_t)ETOT * 4)
#define MS_OFF   (BS_OFF + (size_t)512)
#define LE_OFF   (MS_OFF + (size_t)256)
#define WCH_OFF  (LE_OFF + (size_t)2048)
#define WCL_OFF  (WCH_OFF + (size_t)3 * 512 * 256 * 2)
#define WEH_OFF  (WCL_OFF + (size_t)3 * 512 * 256 * 2)
#define WEL_OFF  (WEH_OFF + (size_t)3 * 256 * 64 * 2)

extern "C" void kernel_launch(void* const* d_in, const int* in_sizes, int n_in,
                              void* d_out, int out_size, void* d_ws, size_t ws_size,
                              hipStream_t stream) {
    const float* x     = (const float*)d_in[0];
    const int*   ei    = (const int*)d_in[1];
    const float* eattr = (const float*)d_in[2];
    const int*   batch = (const int*)d_in[3];
    const float* Wl    = (const float*)d_in[4];
    const float* bl    = (const float*)d_in[5];
    const float* Wr    = (const float*)d_in[6];
    const float* br    = (const float*)d_in[7];
    const float* We    = (const float*)d_in[8];
    const float* att   = (const float*)d_in[9];
    const float* bias  = (const float*)d_in[10];
    const float* Wp1   = (const float*)d_in[11];
    const float* bp1   = (const float*)d_in[12];
    const float* Wp2   = (const float*)d_in[13];
    const float* bp2   = (const float*)d_in[14];

    char* ws = (char*)d_ws;
    float*    w0      = (float*)(ws + W0_OFF);
    float*    xl      = (float*)(ws + XL_OFF);
    short*    xlb     = (short*)(ws + XLB_OFF);
    short*    xrb     = (short*)(ws + XRB_OFF);
    short*    ematb   = (short*)(ws + EMB_OFF);
    float*    plog    = (float*)(ws + LG_OFF);
    float*    alpha   = (float*)(ws + AL_OFF);
    unsigned* lmaxkey = (unsigned*)(ws + LM_OFF);
    float*    denom   = (float*)(ws + DN_OFF);
    int*      deg     = (int*)(ws + DG_OFF);
    int*      off     = (int*)(ws + OF_OFF);
    int*      cursor  = (int*)(ws + CU_OFF);
    int*      csr     = (int*)(ws + CS_OFF);
    int*      srcs    = (int*)(ws + SR_OFF);
    int*      pose    = (int*)(ws + PE_OFF);
    int*      bsum    = (int*)(ws + BS_OFF);
    float*    meansum = (float*)(ws + MS_OFF);
    float*    loope   = (float*)(ws + LE_OFF);
    short*    wcatH   = (short*)(ws + WCH_OFF);
    short*    wcatL   = (short*)(ws + WCL_OFF);
    short*    weH     = (short*)(ws + WEH_OFF);
    short*    weL     = (short*)(ws + WEL_OFF);

    // setup
    hipMemsetAsync(meansum, 0, 64 * 4, stream);
    hipMemsetAsync(deg, 0, (size_t)N_ * 4, stream);
    mean_kernel<<<512, 256, 0, stream>>>(eattr, meansum);
    prep_wcat_kernel<<<(3 * 512 * 256 + 255) / 256, 256, 0, stream>>>(Wl, Wr, wcatH, wcatL);
    prep_we_kernel<<<(3 * 256 * 64 + 255) / 256, 256, 0, stream>>>(We, weH, weL);
    hist_kernel<<<(ETOT + 255) / 256, 256, 0, stream>>>(ei, deg);
    scanA_kernel<<<NB_SCAN, 256, 0, stream>>>(deg, off, bsum);
    scanB_kernel<<<1, 64, 0, stream>>>(bsum);
    scanC_kernel<<<(N_ + 255) / 256, 256, 0, stream>>>(off, bsum);
    hipMemcpyAsync(cursor, off, (size_t)N_ * 4, hipMemcpyDeviceToDevice, stream);
    scatter_kernel<<<(ETOT + 255) / 256, 256, 0, stream>>>(ei, cursor, csr, srcs, pose);

    const dim3 gemmN_grid((N_ + BM - 1) / BM, 4);       // fused xl|xr, N=512
    const dim3 gemmE_grid((CHUNK_E + BM - 1) / BM, 2);  // N=256

    for (int l = 0; l < 3; l++) {
        const float* xin = (l == 0) ? x : w0;
        const float* We_l = We + (size_t)l * 64 * 256;
        const float* att_l = att + (size_t)l * 256;
        loope_kernel<<<1, 256, 0, stream>>>(meansum, We_l, loope);
        // xl (fp32+bf16) | xr (bf16 only)
        mfma_gemm_kernel<<<gemmN_grid, 256, 0, stream>>>(
            xin, wcatH + (size_t)l * 512 * 256, wcatL + (size_t)l * 512 * 256,
            xl, xlb, xrb, bl + (size_t)l * 256, br + (size_t)l * 256, N_, 256);
        hipMemsetAsync(lmaxkey, 0, (size_t)N_ * 4 * 4, stream);
        hipMemsetAsync(denom, 0, (size_t)N_ * 4 * 4, stream);
        for (int c = 0; c < N_CHUNKS; c++) {
            int c0 = c * CHUNK_E;
            mfma_gemm_kernel<<<gemmE_grid, 256, 0, stream>>>(
                eattr + (size_t)c0 * 64, weH + (size_t)l * 256 * 64, weL + (size_t)l * 256 * 64,
                nullptr, ematb, nullptr, nullptr, nullptr, CHUNK_E, 64);
            logits_chunk_kernel<<<(CHUNK_E + 3) / 4, 256, 0, stream>>>(xlb, xrb, ematb, att_l, ei, c0, plog, lmaxkey);
        }
        self_logits_kernel<<<(N_ + 3) / 4, 256, 0, stream>>>(xlb, xrb, loope, att_l, plog, lmaxkey);
        pden_kernel<<<(ETOT * 4 + 255) / 256, 256, 0, stream>>>(ei, plog, lmaxkey, denom);
        alpha_kernel<<<(ETOT * 4 + 255) / 256, 256, 0, stream>>>(ei, pose, plog, denom, alpha);
        agg_kernel<<<N_, 256, 0, stream>>>(xl, alpha, off, srcs, bias + (size_t)l * 256, w0);
    }

    pool_mlp_kernel<<<G_, 256, 0, stream>>>(w0, batch, Wp1, bp1, Wp2, bp2, (float*)d_out);
}

// Round 5
// 2302.565 us; speedup vs baseline: 1.4744x; 1.0543x over previous
//
#include <hip/hip_runtime.h>
#include <hip/hip_bf16.h>

#define N_ 100000
#define E_ 300000
#define ETOT 400000
#define G_ 2048
#define NB_SCAN 98        // ceil(N_/1024)
#define CHUNK_E 50000     // 6 exact chunks of E_
#define N_CHUNKS 6

typedef __attribute__((ext_vector_type(8))) short bf16x8;
typedef __attribute__((ext_vector_type(4))) float f32x4;

__device__ __forceinline__ short f2bf(float f) {
    __hip_bfloat16 h = __float2bfloat16(f);
    return *reinterpret_cast<short*>(&h);
}
__device__ __forceinline__ float bf2f(short s) {
    __hip_bfloat16 h = *reinterpret_cast<__hip_bfloat16*>(&s);
    return __bfloat162float(h);
}

// ---------------- mean of edge_attr over rows -> meansum[64] (sum; divide later)
__global__ __launch_bounds__(256) void mean_kernel(const float* __restrict__ ea, float* __restrict__ meansum) {
    __shared__ float s[256];
    int tid = threadIdx.x;
    int col = tid & 63, rg = tid >> 6;
    float acc = 0.f;
    for (long long row = (long long)blockIdx.x * 4 + rg; row < E_; row += (long long)gridDim.x * 4)
        acc += ea[row * 64 + col];
    s[tid] = acc;
    __syncthreads();
    if (tid < 64) atomicAdd(meansum + tid, s[tid] + s[tid + 64] + s[tid + 128] + s[tid + 192]);
}

// ---------------- loop_e[c] = (meansum/E) @ We_l
__global__ __launch_bounds__(256) void loope_kernel(const float* __restrict__ meansum,
                                                    const float* __restrict__ We_l,
                                                    float* __restrict__ loope) {
    int c = threadIdx.x;
    float acc = 0.f;
    const float invE = 1.0f / (float)E_;
    for (int k = 0; k < 64; k++) acc += (meansum[k] * invE) * We_l[k * 256 + c];
    loope[c] = acc;
}

// ---------------- weight prep: split fp32 -> (hi,lo) bf16, transposed to [n][k]
__global__ __launch_bounds__(256) void prep_wcat_kernel(const float* __restrict__ Wl, const float* __restrict__ Wr,
                                                        short* __restrict__ hi, short* __restrict__ lo) {
    int idx = blockIdx.x * 256 + threadIdx.x;
    if (idx >= 3 * 512 * 256) return;
    int l = idx / (512 * 256);
    int rem = idx % (512 * 256);
    int n = rem >> 8, k = rem & 255;
    float v = (n < 256) ? Wl[((size_t)l * 256 + k) * 256 + n]
                        : Wr[((size_t)l * 256 + k) * 256 + (n - 256)];
    short h = f2bf(v);
    hi[idx] = h;
    lo[idx] = f2bf(v - bf2f(h));
}

__global__ __launch_bounds__(256) void prep_we_kernel(const float* __restrict__ We,
                                                      short* __restrict__ hi, short* __restrict__ lo) {
    int idx = blockIdx.x * 256 + threadIdx.x;
    if (idx >= 3 * 256 * 64) return;
    int l = idx / (256 * 64);
    int rem = idx % (256 * 64);
    int n = rem >> 6, k = rem & 63;
    float v = We[((size_t)l * 64 + k) * 256 + n];
    short h = f2bf(v);
    hi[idx] = h;
    lo[idx] = f2bf(v - bf2f(h));
}

// ---------------- CSR build over dst (self loops e>=E_ have dst = e-E_)
__global__ __launch_bounds__(256) void hist_kernel(const int* __restrict__ ei, int* __restrict__ deg) {
    int e = blockIdx.x * 256 + threadIdx.x;
    if (e >= ETOT) return;
    int d = (e < E_) ? ei[E_ + e] : (e - E_);
    atomicAdd(deg + d, 1);
}

__global__ __launch_bounds__(256) void scanA_kernel(const int* __restrict__ deg, int* __restrict__ off,
                                                    int* __restrict__ bsum) {
    __shared__ int s[256];
    int tid = threadIdx.x;
    int base = blockIdx.x * 1024 + tid * 4;
    int v[4];
#pragma unroll
    for (int i = 0; i < 4; i++) v[i] = (base + i < N_) ? deg[base + i] : 0;
    v[1] += v[0]; v[2] += v[1]; v[3] += v[2];
    s[tid] = v[3];
    __syncthreads();
    for (int o = 1; o < 256; o <<= 1) {
        int t = (tid >= o) ? s[tid - o] : 0;
        __syncthreads();
        s[tid] += t;
        __syncthreads();
    }
    int prev = tid ? s[tid - 1] : 0;
#pragma unroll
    for (int i = 0; i < 4; i++)
        if (base + i < N_) off[base + i + 1] = prev + v[i];
    if (tid == 255) bsum[blockIdx.x] = s[255];
}

__global__ void scanB_kernel(int* __restrict__ bsum) {
    if (threadIdx.x == 0) {
        int run = 0;
        for (int i = 0; i < NB_SCAN; i++) { int t = bsum[i]; bsum[i] = run; run += t; }
    }
}

__global__ __launch_bounds__(256) void scanC_kernel(int* __restrict__ off, const int* __restrict__ bsum) {
    int i = blockIdx.x * 256 + threadIdx.x;
    if (i < N_) {
        off[i + 1] += bsum[i >> 10];
        if (i == 0) off[0] = 0;
    }
}

// scatter: srcs[pos]=src node; pose[e]=pos
__global__ __launch_bounds__(256) void scatter_kernel(const int* __restrict__ ei, int* __restrict__ cursor,
                                                      int* __restrict__ srcs, int* __restrict__ pose) {
    int e = blockIdx.x * 256 + threadIdx.x;
    if (e >= ETOT) return;
    int s, d;
    if (e < E_) { s = ei[e]; d = ei[E_ + e]; }
    else        { s = e - E_; d = s; }
    int pos = atomicAdd(cursor + d, 1);
    srcs[pos] = s;
    pose[e] = pos;
}

// ---------------- split-bf16 MFMA GEMM (templated pass count)
// C[M,*] = A[M,K](fp32) @ B^T(hi/lo bf16 [n][k]).
// SPLIT3: Ahi*Bhi + Ahi*Blo + Alo*Bhi (fp32-accurate); else 1 pass Ahi*Bhi (bf16-accurate).
// Grid: blockIdx.x = n-tile (FAST-varying -> A rows shared by siblings stay LLC-hot),
//       blockIdx.y = m-tile. Tile 128x128, 4 waves (2x2 of 64x64), 16x16x32 MFMA.
// n0<256 -> C0(fp32, opt)+C0b(bf16, opt), bias0; n0>=256 -> C1b(bf16), bias1. ldc=256.
#define BM 128
#define BK 32
#define LDK 40

template <bool SPLIT3>
__global__ __launch_bounds__(256, 3) void mfma_gemm_t(
    const float* __restrict__ A,
    const short* __restrict__ Bt_hi, const short* __restrict__ Bt_lo,
    float* __restrict__ C0, short* __restrict__ C0b, short* __restrict__ C1b,
    const float* __restrict__ bias0, const float* __restrict__ bias1,
    int M, int K) {
    __shared__ short Ahi[BM * LDK];
    __shared__ short Bhi[BM * LDK];
    __shared__ short Alo[SPLIT3 ? BM * LDK : 1];
    __shared__ short Blo[SPLIT3 ? BM * LDK : 1];

    const int tid = threadIdx.x;
    const int n0 = blockIdx.x * BM;
    const int m0 = blockIdx.y * BM;
    const int wave = tid >> 6, lane = tid & 63;
    const int wm = (wave >> 1) * 64, wn = (wave & 1) * 64;
    const int r = lane & 15, q = lane >> 4;

    f32x4 acc[4][4];
#pragma unroll
    for (int i = 0; i < 4; i++)
#pragma unroll
        for (int j = 0; j < 4; j++) acc[i][j] = (f32x4){0.f, 0.f, 0.f, 0.f};

    for (int k0 = 0; k0 < K; k0 += BK) {
        // stage A (fp32 -> hi[/lo] bf16): 128 rows x 32 k
#pragma unroll
        for (int i = 0; i < 4; i++) {
            int li = i * 256 + tid;
            int row = li >> 3, kg = li & 7;
            int gm = m0 + row;
            float4 v = make_float4(0.f, 0.f, 0.f, 0.f);
            if (gm < M) v = *(const float4*)(A + (size_t)gm * K + k0 + kg * 4);
            float f[4] = {v.x, v.y, v.z, v.w};
            short h[4];
#pragma unroll
            for (int j = 0; j < 4; j++) h[j] = f2bf(f[j]);
            *(short4*)(&Ahi[row * LDK + kg * 4]) = make_short4(h[0], h[1], h[2], h[3]);
            if constexpr (SPLIT3) {
                short l[4];
#pragma unroll
                for (int j = 0; j < 4; j++) l[j] = f2bf(f[j] - bf2f(h[j]));
                *(short4*)(&Alo[row * LDK + kg * 4]) = make_short4(l[0], l[1], l[2], l[3]);
            }
        }
        // stage B^T hi[/lo]: 128 n-rows x 32 k
#pragma unroll
        for (int i = 0; i < 2; i++) {
            int li = i * 256 + tid;
            int row = li >> 2, kg = li & 3;
            size_t gofs = (size_t)(n0 + row) * K + k0 + kg * 8;
            *(bf16x8*)(&Bhi[row * LDK + kg * 8]) = *(const bf16x8*)(Bt_hi + gofs);
            if constexpr (SPLIT3)
                *(bf16x8*)(&Blo[row * LDK + kg * 8]) = *(const bf16x8*)(Bt_lo + gofs);
        }
        __syncthreads();
        const int NP = SPLIT3 ? 3 : 1;
#pragma unroll
        for (int pass = 0; pass < NP; pass++) {
            const short* Abuf = (pass == 2) ? Alo : Ahi;
            const short* Bbuf = (pass == 1) ? Blo : Bhi;
            bf16x8 af[4], bfr[4];
#pragma unroll
            for (int f = 0; f < 4; f++) {
                af[f]  = *(const bf16x8*)(Abuf + (wm + f * 16 + r) * LDK + q * 8);
                bfr[f] = *(const bf16x8*)(Bbuf + (wn + f * 16 + r) * LDK + q * 8);
            }
#pragma unroll
            for (int fm = 0; fm < 4; fm++)
#pragma unroll
                for (int fn = 0; fn < 4; fn++)
                    acc[fm][fn] = __builtin_amdgcn_mfma_f32_16x16x32_bf16(af[fm], bfr[fn], acc[fm][fn], 0, 0, 0);
        }
        __syncthreads();
    }

    // epilogue: C/D map col=lane&15, row=q*4+reg
    const bool second = (n0 >= 256);
    const int ncol = second ? n0 - 256 : n0;
    const float* bs = second ? bias1 : bias0;
#pragma unroll
    for (int fm = 0; fm < 4; fm++) {
#pragma unroll
        for (int fn = 0; fn < 4; fn++) {
            int col = ncol + wn + fn * 16 + r;
            float bv = bs ? bs[col] : 0.f;
#pragma unroll
            for (int g = 0; g < 4; g++) {
                int row = m0 + wm + fm * 16 + q * 4 + g;
                if (row < M) {
                    float v = acc[fm][fn][g] + bv;
                    size_t o = (size_t)row * 256 + col;
                    if (second) {
                        C1b[o] = f2bf(v);
                    } else {
                        if (C0)  C0[o] = v;
                        if (C0b) C0b[o] = f2bf(v);
                    }
                }
            }
        }
    }
}

// ---------------- float <-> order-preserving uint key for atomicMax
__device__ __forceinline__ unsigned fkey(float f) {
    unsigned u = __float_as_uint(f);
    return (u & 0x80000000u) ? ~u : (u | 0x80000000u);
}
__device__ __forceinline__ float funkey(unsigned key) {
    return (key & 0x80000000u) ? __uint_as_float(key & 0x7fffffffu) : __uint_as_float(~key);
}

// ---------------- per-edge logits + segment max (bf16 inputs, fp32 math)
// lane handles 4 contiguous cols [lane*4, lane*4+4) -> head = lane>>4; 16-lane reduce.
__global__ __launch_bounds__(256) void logits_chunk_kernel(const short* __restrict__ xlb, const short* __restrict__ xrb,
                                                           const short* __restrict__ ematb, const float* __restrict__ att,
                                                           const int* __restrict__ ei, int c0,
                                                           float* __restrict__ logits, unsigned* __restrict__ lmaxkey) {
    int wid = threadIdx.x >> 6;
    int lane = threadIdx.x & 63;
    int el = blockIdx.x * 4 + wid;
    if (el >= CHUNK_E) return;
    int e = c0 + el;
    int s = ei[e];
    int d = ei[E_ + e];
    short4 a = *(const short4*)(xlb + (size_t)s * 256 + lane * 4);
    short4 b = *(const short4*)(xrb + (size_t)d * 256 + lane * 4);
    short4 c = *(const short4*)(ematb + (size_t)el * 256 + lane * 4);
    float4 w = *(const float4*)(att + lane * 4);
    float m0 = bf2f(a.x) + bf2f(b.x) + bf2f(c.x);
    float m1 = bf2f(a.y) + bf2f(b.y) + bf2f(c.y);
    float m2 = bf2f(a.z) + bf2f(b.z) + bf2f(c.z);
    float m3 = bf2f(a.w) + bf2f(b.w) + bf2f(c.w);
    m0 = (m0 > 0.f) ? m0 : 0.2f * m0;
    m1 = (m1 > 0.f) ? m1 : 0.2f * m1;
    m2 = (m2 > 0.f) ? m2 : 0.2f * m2;
    m3 = (m3 > 0.f) ? m3 : 0.2f * m3;
    float r = m0 * w.x + m1 * w.y + m2 * w.z + m3 * w.w;
#pragma unroll
    for (int o = 1; o < 16; o <<= 1) r += __shfl_xor(r, o, 64);
    if ((lane & 15) == 0) {
        int j = lane >> 4;
        logits[(size_t)e * 4 + j] = r;
        atomicMax(lmaxkey + (size_t)d * 4 + j, fkey(r));
    }
}

// ---------------- self-loop logits (edge id E_+n, src=dst=n, erow=loope fp32)
__global__ __launch_bounds__(256) void self_logits_kernel(const short* __restrict__ xlb, const short* __restrict__ xrb,
                                                          const float* __restrict__ loope, const float* __restrict__ att,
                                                          float* __restrict__ logits, unsigned* __restrict__ lmaxkey) {
    int wid = threadIdx.x >> 6;
    int lane = threadIdx.x & 63;
    int n = blockIdx.x * 4 + wid;
    if (n >= N_) return;
    short4 a = *(const short4*)(xlb + (size_t)n * 256 + lane * 4);
    short4 b = *(const short4*)(xrb + (size_t)n * 256 + lane * 4);
    float4 c = *(const float4*)(loope + lane * 4);
    float4 w = *(const float4*)(att + lane * 4);
    float m0 = bf2f(a.x) + bf2f(b.x) + c.x;
    float m1 = bf2f(a.y) + bf2f(b.y) + c.y;
    float m2 = bf2f(a.z) + bf2f(b.z) + c.z;
    float m3 = bf2f(a.w) + bf2f(b.w) + c.w;
    m0 = (m0 > 0.f) ? m0 : 0.2f * m0;
    m1 = (m1 > 0.f) ? m1 : 0.2f * m1;
    m2 = (m2 > 0.f) ? m2 : 0.2f * m2;
    m3 = (m3 > 0.f) ? m3 : 0.2f * m3;
    float r = m0 * w.x + m1 * w.y + m2 * w.z + m3 * w.w;
#pragma unroll
    for (int o = 1; o < 16; o <<= 1) r += __shfl_xor(r, o, 64);
    if ((lane & 15) == 0) {
        int j = lane >> 4;
        logits[(size_t)(E_ + n) * 4 + j] = r;
        atomicMax(lmaxkey + (size_t)n * 4 + j, fkey(r));
    }
}

// ---------------- p = exp(logit - lmax[dst]); denom[dst] += p  (one thread per edge)
__global__ __launch_bounds__(256) void pden_kernel(const int* __restrict__ ei, float* __restrict__ plog,
                                                   const unsigned* __restrict__ lmaxkey, float* __restrict__ denom) {
    int e = blockIdx.x * 256 + threadIdx.x;
    if (e >= ETOT) return;
    int d = (e < E_) ? ei[E_ + e] : (e - E_);
    float4 lg = *(const float4*)(plog + (size_t)e * 4);
    uint4 km = *(const uint4*)(lmaxkey + (size_t)d * 4);
    float p0 = expf(lg.x - funkey(km.x));
    float p1 = expf(lg.y - funkey(km.y));
    float p2 = expf(lg.z - funkey(km.z));
    float p3 = expf(lg.w - funkey(km.w));
    *(float4*)(plog + (size_t)e * 4) = make_float4(p0, p1, p2, p3);
    atomicAdd(denom + (size_t)d * 4 + 0, p0);
    atomicAdd(denom + (size_t)d * 4 + 1, p1);
    atomicAdd(denom + (size_t)d * 4 + 2, p2);
    atomicAdd(denom + (size_t)d * 4 + 3, p3);
}

// ---------------- alpha_csr[pos][h] = p / denom[dst]  (one thread per edge)
__global__ __launch_bounds__(256) void alpha_kernel(const int* __restrict__ ei, const int* __restrict__ pose,
                                                    const float* __restrict__ plog, const float* __restrict__ denom,
                                                    float* __restrict__ alpha) {
    int e = blockIdx.x * 256 + threadIdx.x;
    if (e >= ETOT) return;
    int d = (e < E_) ? ei[E_ + e] : (e - E_);
    int pos = pose[e];
    float4 dn = *(const float4*)(denom + (size_t)d * 4);
    float4 p = *(const float4*)(plog + (size_t)e * 4);
    float4 al;
    al.x = p.x / (dn.x + 1e-16f);
    al.y = p.y / (dn.y + 1e-16f);
    al.z = p.z / (dn.z + 1e-16f);
    al.w = p.w / (dn.w + 1e-16f);
    *(float4*)(alpha + (size_t)pos * 4) = al;
}

// ---------------- CSR aggregation: xout[d] = relu( sum_i alpha[i]*xl[srcs[i]] + bias )
__global__ __launch_bounds__(256) void agg_kernel(const float* __restrict__ xl, const float* __restrict__ alpha,
                                                  const int* __restrict__ off, const int* __restrict__ srcs,
                                                  const float* __restrict__ bias, float* __restrict__ xout) {
    int d = blockIdx.x;
    int t = threadIdx.x;
    int h = t >> 6;
    int s0 = off[d], s1 = off[d + 1];
    float acc = 0.f;
    int i = s0;
    for (; i + 4 <= s1; i += 4) {
        int a0 = srcs[i], a1 = srcs[i + 1], a2 = srcs[i + 2], a3 = srcs[i + 3];
        float w0 = alpha[(size_t)i * 4 + h];
        float w1 = alpha[(size_t)(i + 1) * 4 + h];
        float w2 = alpha[(size_t)(i + 2) * 4 + h];
        float w3 = alpha[(size_t)(i + 3) * 4 + h];
        float x0 = xl[(size_t)a0 * 256 + t];
        float x1 = xl[(size_t)a1 * 256 + t];
        float x2 = xl[(size_t)a2 * 256 + t];
        float x3 = xl[(size_t)a3 * 256 + t];
        acc += w0 * x0 + w1 * x1 + w2 * x2 + w3 * x3;
    }
    for (; i < s1; i++)
        acc += alpha[(size_t)i * 4 + h] * xl[(size_t)srcs[i] * 256 + t];
    float v = acc + bias[t];
    xout[(size_t)d * 256 + t] = v > 0.f ? v : 0.f;
}

// ---------------- per-graph mean pool + 2-layer MLP head
__device__ __forceinline__ int lbound(const int* __restrict__ a, int n, int v) {
    int lo = 0, hi = n;
    while (lo < hi) { int mid = (lo + hi) >> 1; if (a[mid] < v) lo = mid + 1; else hi = mid; }
    return lo;
}

__global__ __launch_bounds__(256) void pool_mlp_kernel(const float* __restrict__ x, const int* __restrict__ batch,
                                                       const float* __restrict__ Wp1, const float* __restrict__ bp1,
                                                       const float* __restrict__ Wp2, const float* __restrict__ bp2,
                                                       float* __restrict__ out) {
    int g = blockIdx.x;
    int t = threadIdx.x;
    int lo = lbound(batch, N_, g);
    int hi = lbound(batch, N_, g + 1);
    float sum = 0.f;
    for (int n = lo; n < hi; n++) sum += x[(size_t)n * 256 + t];
    int cnt = hi - lo;
    float pooled = sum / (float)(cnt > 1 ? cnt : 1);
    __shared__ float sp[256];
    __shared__ float sh[128];
    __shared__ float sw[4];
    sp[t] = pooled;
    __syncthreads();
    if (t < 128) {
        float a = bp1[t];
        for (int k = 0; k < 256; k++) a += sp[k] * Wp1[k * 128 + t];
        sh[t] = a > 0.f ? a : 0.f;
    }
    __syncthreads();
    float v = (t < 128) ? sh[t] * Wp2[t] : 0.f;
#pragma unroll
    for (int o = 32; o; o >>= 1) v += __shfl_xor(v, o, 64);
    if ((t & 63) == 0) sw[t >> 6] = v;
    __syncthreads();
    if (t == 0) out[g] = sw[0] + sw[1] + sw[2] + sw[3] + bp2[0];
}

// ---------------- workspace layout (bytes), total ~356 MB
#define W0_OFF   ((size_t)0)                               // layer io      102.4 MB
#define XL_OFF   (W0_OFF + (size_t)N_ * 256 * 4)           // xl fp32       102.4 MB
#define XLB_OFF  (XL_OFF + (size_t)N_ * 256 * 4)           // xl bf16        51.2 MB
#define XRB_OFF  (XLB_OFF + (size_t)N_ * 256 * 2)          // xr bf16        51.2 MB
#define EMB_OFF  (XRB_OFF + (size_t)N_ * 256 * 2)          // emat chunk bf16 25.6 MB
#define LG_OFF   (EMB_OFF + (size_t)CHUNK_E * 256 * 2)     // plog            6.4 MB
#define AL_OFF   (LG_OFF + (size_t)ETOT * 4 * 4)           // alpha_csr       6.4 MB
#define LM_OFF   (AL_OFF + (size_t)ETOT * 4 * 4)           // lmax keys
#define DN_OFF   (LM_OFF + (size_t)N_ * 4 * 4)             // denom
#define DG_OFF   (DN_OFF + (size_t)N_ * 4 * 4)             // deg
#define OF_OFF   (DG_OFF + (size_t)N_ * 4)                 // off
#define CU_OFF   (OF_OFF + (size_t)(N_ + 32) * 4)          // cursor
#define SR_OFF   (CU_OFF + (size_t)N_ * 4)                 // srcs
#define PE_OFF   (SR_OFF + (size_t)ETOT * 4)               // pose
#define BS_OFF   (PE_OFF + (size_t)ETOT * 4)
#define MS_OFF   (BS_OFF + (size_t)512)
#define LE_OFF   (MS_OFF + (size_t)256)
#define WCH_OFF  (LE_OFF + (size_t)2048)
#define WCL_OFF  (WCH_OFF + (size_t)3 * 512 * 256 * 2)
#define WEH_OFF  (WCL_OFF + (size_t)3 * 512 * 256 * 2)
#define WEL_OFF  (WEH_OFF + (size_t)3 * 256 * 64 * 2)

extern "C" void kernel_launch(void* const* d_in, const int* in_sizes, int n_in,
                              void* d_out, int out_size, void* d_ws, size_t ws_size,
                              hipStream_t stream) {
    const float* x     = (const float*)d_in[0];
    const int*   ei    = (const int*)d_in[1];
    const float* eattr = (const float*)d_in[2];
    const int*   batch = (const int*)d_in[3];
    const float* Wl    = (const float*)d_in[4];
    const float* bl    = (const float*)d_in[5];
    const float* Wr    = (const float*)d_in[6];
    const float* br    = (const float*)d_in[7];
    const float* We    = (const float*)d_in[8];
    const float* att   = (const float*)d_in[9];
    const float* bias  = (const float*)d_in[10];
    const float* Wp1   = (const float*)d_in[11];
    const float* bp1   = (const float*)d_in[12];
    const float* Wp2   = (const float*)d_in[13];
    const float* bp2   = (const float*)d_in[14];

    char* ws = (char*)d_ws;
    float*    w0      = (float*)(ws + W0_OFF);
    float*    xl      = (float*)(ws + XL_OFF);
    short*    xlb     = (short*)(ws + XLB_OFF);
    short*    xrb     = (short*)(ws + XRB_OFF);
    short*    ematb   = (short*)(ws + EMB_OFF);
    float*    plog    = (float*)(ws + LG_OFF);
    float*    alpha   = (float*)(ws + AL_OFF);
    unsigned* lmaxkey = (unsigned*)(ws + LM_OFF);
    float*    denom   = (float*)(ws + DN_OFF);
    int*      deg     = (int*)(ws + DG_OFF);
    int*      off     = (int*)(ws + OF_OFF);
    int*      cursor  = (int*)(ws + CU_OFF);
    int*      srcs    = (int*)(ws + SR_OFF);
    int*      pose    = (int*)(ws + PE_OFF);
    int*      bsum    = (int*)(ws + BS_OFF);
    float*    meansum = (float*)(ws + MS_OFF);
    float*    loope   = (float*)(ws + LE_OFF);
    short*    wcatH   = (short*)(ws + WCH_OFF);
    short*    wcatL   = (short*)(ws + WCL_OFF);
    short*    weH     = (short*)(ws + WEH_OFF);
    short*    weL     = (short*)(ws + WEL_OFF);

    // setup
    hipMemsetAsync(meansum, 0, 64 * 4, stream);
    hipMemsetAsync(deg, 0, (size_t)N_ * 4, stream);
    mean_kernel<<<512, 256, 0, stream>>>(eattr, meansum);
    prep_wcat_kernel<<<(3 * 512 * 256 + 255) / 256, 256, 0, stream>>>(Wl, Wr, wcatH, wcatL);
    prep_we_kernel<<<(3 * 256 * 64 + 255) / 256, 256, 0, stream>>>(We, weH, weL);
    hist_kernel<<<(ETOT + 255) / 256, 256, 0, stream>>>(ei, deg);
    scanA_kernel<<<NB_SCAN, 256, 0, stream>>>(deg, off, bsum);
    scanB_kernel<<<1, 64, 0, stream>>>(bsum);
    scanC_kernel<<<(N_ + 255) / 256, 256, 0, stream>>>(off, bsum);
    hipMemcpyAsync(cursor, off, (size_t)N_ * 4, hipMemcpyDeviceToDevice, stream);
    scatter_kernel<<<(ETOT + 255) / 256, 256, 0, stream>>>(ei, cursor, srcs, pose);

    const dim3 gemmN_grid(4, (N_ + BM - 1) / BM);       // n-tile fast, m-tile slow
    const dim3 gemmE_grid(2, (CHUNK_E + BM - 1) / BM);

    for (int l = 0; l < 3; l++) {
        const float* xin = (l == 0) ? x : w0;
        const float* We_l = We + (size_t)l * 64 * 256;
        const float* att_l = att + (size_t)l * 256;
        loope_kernel<<<1, 256, 0, stream>>>(meansum, We_l, loope);
        // xl (fp32+bf16) | xr (bf16 only), fp32-split path
        mfma_gemm_t<true><<<gemmN_grid, 256, 0, stream>>>(
            xin, wcatH + (size_t)l * 512 * 256, wcatL + (size_t)l * 512 * 256,
            xl, xlb, xrb, bl + (size_t)l * 256, br + (size_t)l * 256, N_, 256);
        hipMemsetAsync(lmaxkey, 0, (size_t)N_ * 4 * 4, stream);
        hipMemsetAsync(denom, 0, (size_t)N_ * 4 * 4, stream);
        for (int c = 0; c < N_CHUNKS; c++) {
            int c0 = c * CHUNK_E;
            // emat is stored bf16 anyway -> 1-pass (hi*hi) is precision-equivalent
            mfma_gemm_t<false><<<gemmE_grid, 256, 0, stream>>>(
                eattr + (size_t)c0 * 64, weH + (size_t)l * 256 * 64, weL + (size_t)l * 256 * 64,
                nullptr, ematb, nullptr, nullptr, nullptr, CHUNK_E, 64);
            logits_chunk_kernel<<<(CHUNK_E + 3) / 4, 256, 0, stream>>>(xlb, xrb, ematb, att_l, ei, c0, plog, lmaxkey);
        }
        self_logits_kernel<<<(N_ + 3) / 4, 256, 0, stream>>>(xlb, xrb, loope, att_l, plog, lmaxkey);
        pden_kernel<<<(ETOT + 255) / 256, 256, 0, stream>>>(ei, plog, lmaxkey, denom);
        alpha_kernel<<<(ETOT + 255) / 256, 256, 0, stream>>>(ei, pose, plog, denom, alpha);
        agg_kernel<<<N_, 256, 0, stream>>>(xl, alpha, off, srcs, bias + (size_t)l * 256, w0);
    }

    pool_mlp_kernel<<<G_, 256, 0, stream>>>(w0, batch, Wp1, bp1, Wp2, bp2, (float*)d_out);
}